// Round 2
// baseline (4634.598 us; speedup 1.0000x reference)
//
#include <hip/hip_runtime.h>
#include <math.h>

// ============================================================================
// ConflictNet: 30-step graph-PDE scan, B=2, N=8000, DY=12.
// Round 2: 4 nodes per wave; MLP activation broadcast via per-wave LDS rows
// (uniform-address ds_read_b128) instead of v_readlane; weight loads amortized
// across the 4 nodes; __launch_bounds__(256,4) for register headroom.
// ============================================================================

namespace {
constexpr int NB = 2;
constexpr int NN = 8000;
constexpr int BN = NB * NN;   // 16000
constexpr int TS = 30;
constexpr int CAP = 96;       // reverse-adjacency capacity
constexpr int NPW = 4;        // nodes per wave

// workspace float offsets
constexpr int O_COEFF = 0;              // 12x12 coeffM
constexpr int O_DIJ   = 144;            // 12
constexpr int O_MUIJ  = 156;            // 12
constexpr int O_MC    = 168;            // 12  (MUij @ coeffM)
constexpr int O_GPX   = 256;            // BN
constexpr int O_GPY   = O_GPX + BN;
constexpr int O_H1T   = O_GPY + BN;     // BN*64  trans layer-0 static (incl bias)
constexpr int O_H1Q   = O_H1T + BN*64;  // BN*64  q layer-0 static
constexpr int O_H1D   = O_H1Q + BN*64;  // BN*32  dec layer-0 static
constexpr int O_FEATA = O_H1D + BN*32;  // BN*12
constexpr int O_FEATB = O_FEATA + BN*12;
constexpr int O_AXYA  = O_FEATB + BN*12; // BN*24 (ax[12], ay[12])
constexpr int O_AXYB  = O_AXYA + BN*24;
constexpr int O_FLTEND= O_AXYB + BN*24;
// int region (after float region): rev counts [BN], rev entries [BN*CAP]

// output flat offsets
constexpr int OUS  = 0;                 // us   (B,N,1,T)
constexpr int OMIX = BN*TS;             // mix  (B,N,1,T)
constexpr int OQ0  = 2*BN*TS;           // q0_m (B,N,12,1,T)
constexpr int OFD  = OQ0 + BN*12*TS;    // fd   (B,N,1,T,12)

// LDS layout per node-slot (floats); all offsets multiple of 4 floats (16 B)
constexpr int L_AG   = 0;    // 24  (feat 0-11, wsum 12-23)
constexpr int L_H1   = 24;   // 128 (h1t 0-63, h1q 64-127)
constexpr int L_H2   = 152;  // 64  (h2t 0-31, h2q 32-63)
constexpr int L_NV   = 216;  // 16  (newv 0-11, pad)
constexpr int L_D1   = 232;  // 32
constexpr int L_D2   = 264;  // 32
constexpr int L_SLOT = 296;  // 1184 B per node
}

__device__ __forceinline__ float group5_sum(float v, int lane) {
  // lanes are (g, c) = (lane/12, lane%12), g<5 active; sum across the 5 groups.
  int g = lane / 12, c = lane % 12;
  float s1 = __shfl(v, c + 12*((g+1)%5));
  float s2 = __shfl(v, c + 12*((g+2)%5));
  float s3 = __shfl(v, c + 12*((g+3)%5));
  float s4 = __shfl(v, c + 12*((g+4)%5));
  return v + s1 + s2 + s3 + s4;
}

// ---------------------------------------------------------------------------
// S1: coeffM (12x12), Dij, MUij, MC = MUij @ coeffM
// ---------------------------------------------------------------------------
__global__ void k_setup_small(const float* __restrict__ D, const float* __restrict__ mu,
                              const float* __restrict__ cv, float* ws) {
  int t = threadIdx.x;
  for (int e = t; e < 144; e += 256) {
    int r = e / 12, q = e % 12;
    int rb = r >> 2, cb = q >> 2, ri = r & 3, qi = q & 3;
    float val = 0.f;
    if (rb == cb) {
      int f = ri*4 + qi;
      if (f % 5 == 0) val = 1.f;
      else val = cv[64 + rb*12 + (f/5)*4 + (f%5) - 1];
    } else if (rb == 0 && cb == 2) val = cv[     ri*4 + qi];
    else if   (rb == 1 && cb == 2) val = cv[16 + ri*4 + qi];
    else if   (rb == 2 && cb == 0) val = cv[32 + ri*4 + qi];
    else if   (rb == 2 && cb == 1) val = cv[48 + ri*4 + qi];
    ws[O_COEFF + e] = fmaxf(val, 0.f);
  }
  if (t < 12) {
    ws[O_DIJ + t]  = (t < 4) ? 0.f : fmaxf(D[t-4], 0.f);
    ws[O_MUIJ + t] = (t < 4) ? fmaxf(mu[t], 0.f) : ((t < 8) ? 0.f : fmaxf(mu[t-4], 0.f));
  }
  __syncthreads();
  if (t < 12) {
    float acc = 0.f;
    for (int c = 0; c < 12; c++) acc += ws[O_MUIJ + c] * ws[O_COEFF + c*12 + t];
    ws[O_MC + t] = acc;
  }
}

// ---------------------------------------------------------------------------
// S2: per-node invariants (wave per node; runs once)
// ---------------------------------------------------------------------------
__global__ __launch_bounds__(256) void k_setup_node(
    const float* __restrict__ phi, const float* __restrict__ feat_dy,
    const float* __restrict__ feat_st,
    const int* __restrict__ adj4, const int* __restrict__ adj25,
    const float* __restrict__ Wt0, const float* __restrict__ bt0,
    const float* __restrict__ Wq0, const float* __restrict__ bq0,
    const float* __restrict__ Wd0, const float* __restrict__ bd0,
    float* ws, int* wsi) {
  const int wid  = (blockIdx.x * blockDim.x + threadIdx.x) >> 6;
  const int lane = threadIdx.x & 63;
  if (wid >= BN) return;
  const int b = wid / NN, n = wid % NN;

  const int* a4 = adj4 + n*4;
  const float gpx = phi[b*NN + a4[1]] - phi[b*NN + a4[0]];
  const float gpy = phi[b*NN + a4[3]] - phi[b*NN + a4[2]];
  if (lane == 0) { ws[O_GPX + wid] = gpx; ws[O_GPY + wid] = gpy; wsi[wid] = 0; }

  int idx = 0; float w = 0.f;
  if (lane < 25) { idx = adj25[n*25 + lane]; w = (lane == 0) ? 1.f : 0.01f; }
  float phiw = (lane < 25) ? w * phi[b*NN + idx] : 0.f;
  #pragma unroll
  for (int s = 32; s > 0; s >>= 1) phiw += __shfl_xor(phiw, s);

  float stv[6], stw[6];
  #pragma unroll
  for (int j = 0; j < 6; j++) {
    float x = (lane < 25) ? w * feat_st[(b*NN + idx)*6 + j] : 0.f;
    #pragma unroll
    for (int s = 32; s > 0; s >>= 1) x += __shfl_xor(x, s);
    stw[j] = x;
    stv[j] = feat_st[(b*NN + n)*6 + j];
  }
  const float phiv = phi[b*NN + n];

  float hT = bt0[lane] + phiv*Wt0[24*64 + lane] + phiw*Wt0[25*64 + lane];
  float hQ = bq0[lane] + phiv*Wq0[24*64 + lane] + phiw*Wq0[25*64 + lane];
  #pragma unroll
  for (int i = 0; i < 12; i++) {
    hT = fmaf(ws[O_DIJ  + i], Wt0[(26+i)*64 + lane], hT);
    hT = fmaf(ws[O_MUIJ + i], Wt0[(38+i)*64 + lane], hT);
  }
  #pragma unroll
  for (int j = 0; j < 6; j++) {
    hT = fmaf(stv[j], Wt0[(50+j)*64 + lane], hT);
    hT = fmaf(stw[j], Wt0[(56+j)*64 + lane], hT);
    hQ = fmaf(stv[j], Wq0[(26+j)*64 + lane], hQ);
    hQ = fmaf(stw[j], Wq0[(32+j)*64 + lane], hQ);
  }
  ws[O_H1T + wid*64 + lane] = hT;
  ws[O_H1Q + wid*64 + lane] = hQ;
  if (lane < 32) {
    float hD = bd0[lane];
    #pragma unroll
    for (int j = 0; j < 6; j++) hD = fmaf(stv[j], Wd0[(12+j)*32 + lane], hD);
    ws[O_H1D + wid*32 + lane] = hD;
  }
  if (lane < 12) {
    float f = feat_dy[wid*12 + lane];
    ws[O_FEATA + wid*12 + lane] = f;
    float mass = (f == 0.f) ? 1.f : f;
    float mc = ws[O_MC + lane];
    ws[O_AXYA + wid*24 + lane]      = fminf(fmaxf(gpx*mc/mass, -2.f), 2.f);
    ws[O_AXYA + wid*24 + 12 + lane] = fminf(fmaxf(gpy*mc/mass, -2.f), 2.f);
  }
}

// ---------------------------------------------------------------------------
// S3: build reverse adjacency for the scatter (per batch).
// ---------------------------------------------------------------------------
__global__ void k_build_rev(const int* __restrict__ adj25, int* wsi) {
  int i = blockIdx.x * blockDim.x + threadIdx.x;
  if (i >= BN * 25) return;
  int b = i / (NN * 25);
  int rem = i % (NN * 25);
  int m = rem / 25, k = rem % 25;
  int tgt = adj25[i];
  int slot = atomicAdd(&wsi[b*NN + tgt], 1);
  if (slot < CAP) wsi[BN + (b*NN + tgt)*CAP + slot] = (m << 5) | k;
}

// ---------------------------------------------------------------------------
// Step kernel: one scan iteration.  4 nodes per wave, LDS act broadcast.
// ---------------------------------------------------------------------------
__global__ __launch_bounds__(256, 4) void k_step(
    const float* __restrict__ ws, const int* __restrict__ rcnt,
    const int* __restrict__ rent, int t,
    const float* __restrict__ fsrc, const float* __restrict__ axsrc,
    float* __restrict__ fdst, float* __restrict__ axdst,
    const int* __restrict__ adj4, const int* __restrict__ adj25,
    const float* __restrict__ Wt0, const float* __restrict__ Wq0,
    const float* __restrict__ Wt1, const float* __restrict__ bt1,
    const float* __restrict__ Wq1, const float* __restrict__ bq1,
    const float* __restrict__ Wt2, const float* __restrict__ bt2,
    const float* __restrict__ Wq2, const float* __restrict__ bq2,
    const float* __restrict__ Wd0, const float* __restrict__ Wd1,
    const float* __restrict__ bd1, const float* __restrict__ Wd2,
    const float* __restrict__ bd2, const float* __restrict__ Wd3,
    const float* __restrict__ bd3, float* __restrict__ out) {
  __shared__ __attribute__((aligned(16))) float sh[4 * NPW * L_SLOT];
  const int wslot = threadIdx.x >> 6;
  const int lane  = threadIdx.x & 63;
  const int wid   = blockIdx.x * 4 + wslot;   // wave id, 0..3999
  const int nb    = wid * NPW;                // base node (all 4 in same batch)
  const int b  = nb / NN;
  const int n0 = nb % NN;
  const int c12 = lane % 12;
  const int g   = lane / 12;
  float* shs = sh + wslot * (NPW * L_SLOT);

  const float dij  = ws[O_DIJ  + c12];
  const float muij = ws[O_MUIJ + c12];
  float cfv[12];
  #pragma unroll
  for (int cc = 0; cc < 12; cc++) cfv[cc] = ws[O_COEFF + cc*12 + c12];

  // ---- feat + 25-neighbor weighted aggregate ----
  float f_c[NPW];
  #pragma unroll
  for (int j = 0; j < NPW; j++) {
    const int n = n0 + j;
    f_c[j] = fsrc[(b*NN + n)*12 + c12];
    float agw = 0.f;
    if (g < 5) {
      const int* a0 = adj25 + n*25;
      #pragma unroll
      for (int kk = 0; kk < 5; kk++) {
        int k = g + 5*kk;
        float wgt = (k == 0) ? 1.f : 0.01f;
        agw = fmaf(wgt, fsrc[(b*NN + a0[k])*12 + c12], agw);
      }
    }
    agw = group5_sum(agw, lane);
    float AG = (lane < 12) ? f_c[j] : agw;
    if (lane < 24) shs[j*L_SLOT + L_AG + lane] = AG;
  }

  // ---- stencil: J, Fdiv, v; udiff = v @ coeffM ----
  float udiff[NPW];
  {
    float vsv[NPW];
    #pragma unroll
    for (int j = 0; j < NPW; j++) {
      const int n = n0 + j;
      const int* a4p = adj4 + n*4;
      const int m0 = a4p[0], m1 = a4p[1], m2 = a4p[2], m3 = a4p[3];
      const float f0 = fsrc[(b*NN+m0)*12 + c12];
      const float f1 = fsrc[(b*NN+m1)*12 + c12];
      const float f2 = fsrc[(b*NN+m2)*12 + c12];
      const float f3 = fsrc[(b*NN+m3)*12 + c12];
      const float J = 4.f * ((f0+f1+f2+f3) - 4.f*f_c[j]);
      const float gx0 = ws[O_GPX + b*NN + m0], gx1 = ws[O_GPX + b*NN + m1];
      const float gy2 = ws[O_GPY + b*NN + m2], gy3 = ws[O_GPY + b*NN + m3];
      const float Fdiv = gx1*f1 - gx0*f0 + gy3*f3 - gy2*f2;
      vsv[j] = dij*J - muij*Fdiv;
    }
    #pragma unroll
    for (int j = 0; j < NPW; j++) {
      float acc = 0.f;
      #pragma unroll
      for (int cc = 0; cc < 12; cc++) acc = fmaf(__shfl(vsv[j], cc), cfv[cc], acc);
      udiff[j] = acc;
    }
  }

  // ---- u_rig via reverse-adjacency gather ----
  float urig[NPW];
  #pragma unroll
  for (int j = 0; j < NPW; j++) {
    const int wnode = nb + j;
    int cnt = rcnt[wnode]; if (cnt > CAP) cnt = CAP;
    const int* re = rent + wnode*CAP;
    float usc = 0.f;
    if (g < 5) {
      for (int e = g; e < cnt; e += 5) {
        int pk = re[e];
        int m = pk >> 5, k = pk & 31;
        float kx = (float)(k - (k/5)*5);
        float ky = (float)(k/5);
        int base = b*NN + m;
        float fm = fsrc[base*12 + c12];
        float ax = axsrc[base*24 + c12];
        float ay = axsrc[base*24 + 12 + c12];
        float px = fmaxf(1.f - fabsf(ax - kx), 0.f);
        float py = fmaxf(1.f - fabsf(ay - ky), 0.f);
        usc = fmaf(px*py, fm, usc);
      }
    }
    usc = group5_sum(usc, lane);
    urig[j] = usc - f_c[j];
  }

  // ---- trans & q hidden-1 (static part precomputed; 24 dynamic rows) ----
  float h1t[NPW], h1q[NPW];
  #pragma unroll
  for (int j = 0; j < NPW; j++) {
    h1t[j] = ws[O_H1T + (nb+j)*64 + lane];
    h1q[j] = ws[O_H1Q + (nb+j)*64 + lane];
  }
  #pragma unroll
  for (int i4 = 0; i4 < 24; i4 += 4) {
    float wt[4], wq[4];
    #pragma unroll
    for (int r = 0; r < 4; r++) {
      wt[r] = Wt0[(i4+r)*64 + lane];
      wq[r] = Wq0[(i4+r)*64 + lane];
    }
    #pragma unroll
    for (int j = 0; j < NPW; j++) {
      const float4 a = *(const float4*)&shs[j*L_SLOT + L_AG + i4];
      h1t[j] = fmaf(a.x, wt[0], h1t[j]); h1q[j] = fmaf(a.x, wq[0], h1q[j]);
      h1t[j] = fmaf(a.y, wt[1], h1t[j]); h1q[j] = fmaf(a.y, wq[1], h1q[j]);
      h1t[j] = fmaf(a.z, wt[2], h1t[j]); h1q[j] = fmaf(a.z, wq[2], h1q[j]);
      h1t[j] = fmaf(a.w, wt[3], h1t[j]); h1q[j] = fmaf(a.w, wq[3], h1q[j]);
    }
  }
  #pragma unroll
  for (int j = 0; j < NPW; j++) {
    shs[j*L_SLOT + L_H1 + lane]      = fmaxf(h1t[j], 0.f);
    shs[j*L_SLOT + L_H1 + 64 + lane] = fmaxf(h1q[j], 0.f);
  }

  // ---- hidden-2: lanes 0-31 trans, 32-63 q; acts broadcast from LDS ----
  const int l32 = lane & 31;
  const bool isQ = lane >= 32;
  const float* W1p = (isQ ? Wq1 : Wt1) + l32;
  const int hoff = isQ ? 64 : 0;
  const float h2b = isQ ? bq1[l32] : bt1[l32];
  float h2[NPW];
  #pragma unroll
  for (int j = 0; j < NPW; j++) h2[j] = h2b;
  #pragma unroll
  for (int i4 = 0; i4 < 64; i4 += 4) {
    float w1[4];
    #pragma unroll
    for (int r = 0; r < 4; r++) w1[r] = W1p[(i4+r)*32];
    #pragma unroll
    for (int j = 0; j < NPW; j++) {
      const float4 a = *(const float4*)&shs[j*L_SLOT + L_H1 + hoff + i4];
      h2[j] = fmaf(a.x, w1[0], h2[j]);
      h2[j] = fmaf(a.y, w1[1], h2[j]);
      h2[j] = fmaf(a.z, w1[2], h2[j]);
      h2[j] = fmaf(a.w, w1[3], h2[j]);
    }
  }
  #pragma unroll
  for (int j = 0; j < NPW; j++)
    shs[j*L_SLOT + L_H2 + lane] = fmaxf(h2[j], 0.f);

  // ---- mix logit (col 25 of Wt2) + q0 (channel c12 per lane) ----
  float mixz[NPW], q0[NPW];
  const float* Wq2p = Wq2 + c12;
  const float mzb = bt2[25];
  const float q0b = bq2[c12];
  #pragma unroll
  for (int j = 0; j < NPW; j++) { mixz[j] = mzb; q0[j] = q0b; }
  #pragma unroll
  for (int i4 = 0; i4 < 32; i4 += 4) {
    float wz[4], wq[4];
    #pragma unroll
    for (int r = 0; r < 4; r++) {
      wz[r] = Wt2[(i4+r)*26 + 25];   // uniform -> scalar load
      wq[r] = Wq2p[(i4+r)*12];
    }
    #pragma unroll
    for (int j = 0; j < NPW; j++) {
      const float4 at = *(const float4*)&shs[j*L_SLOT + L_H2 + i4];
      const float4 aq = *(const float4*)&shs[j*L_SLOT + L_H2 + 32 + i4];
      mixz[j] = fmaf(at.x, wz[0], mixz[j]); q0[j] = fmaf(aq.x, wq[0], q0[j]);
      mixz[j] = fmaf(at.y, wz[1], mixz[j]); q0[j] = fmaf(aq.y, wq[1], q0[j]);
      mixz[j] = fmaf(at.z, wz[2], mixz[j]); q0[j] = fmaf(aq.z, wq[2], q0[j]);
      mixz[j] = fmaf(at.w, wz[3], mixz[j]); q0[j] = fmaf(aq.w, wq[3], q0[j]);
    }
  }

  // ---- update, outputs, next-step ax/ay ----
  float newv[NPW];
  #pragma unroll
  for (int j = 0; j < NPW; j++) {
    const int bn = nb + j;
    const float mix = 1.f / (1.f + expf(-mixz[j]));
    newv[j] = f_c[j] + mix*udiff[j] + (1.f - mix)*urig[j] + q0[j];
    if (lane < 12) {
      shs[j*L_SLOT + L_NV + lane] = newv[j];
      out[OQ0 + (bn*12 + lane)*TS + t] = q0[j];
      out[OFD + (bn*TS + t)*12 + lane] = newv[j];
      fdst[bn*12 + lane] = newv[j];
      float mass = (newv[j] == 0.f) ? 1.f : newv[j];
      float mc = ws[O_MC + lane];
      float gpxn = ws[O_GPX + bn], gpyn = ws[O_GPY + bn];
      axdst[bn*24 + lane]      = fminf(fmaxf(gpxn*mc/mass, -2.f), 2.f);
      axdst[bn*24 + 12 + lane] = fminf(fmaxf(gpyn*mc/mass, -2.f), 2.f);
    }
    if (lane == 0) out[OMIX + bn*TS + t] = mix;
  }

  // ---- dec MLP: 12(+static) -> 32 -> 32 -> 64 -> 1 ----
  float d1[NPW];
  #pragma unroll
  for (int j = 0; j < NPW; j++) d1[j] = ws[O_H1D + (nb+j)*32 + l32];
  #pragma unroll
  for (int i4 = 0; i4 < 12; i4 += 4) {
    float wd[4];
    #pragma unroll
    for (int r = 0; r < 4; r++) wd[r] = Wd0[(i4+r)*32 + l32];
    #pragma unroll
    for (int j = 0; j < NPW; j++) {
      const float4 a = *(const float4*)&shs[j*L_SLOT + L_NV + i4];
      d1[j] = fmaf(a.x, wd[0], d1[j]);
      d1[j] = fmaf(a.y, wd[1], d1[j]);
      d1[j] = fmaf(a.z, wd[2], d1[j]);
      d1[j] = fmaf(a.w, wd[3], d1[j]);
    }
  }
  #pragma unroll
  for (int j = 0; j < NPW; j++) {
    d1[j] = fmaxf(d1[j], 0.f);
    if (lane < 32) shs[j*L_SLOT + L_D1 + lane] = d1[j];
  }

  float d2[NPW];
  const float d2b = bd1[l32];
  #pragma unroll
  for (int j = 0; j < NPW; j++) d2[j] = d2b;
  #pragma unroll
  for (int i4 = 0; i4 < 32; i4 += 4) {
    float wd[4];
    #pragma unroll
    for (int r = 0; r < 4; r++) wd[r] = Wd1[(i4+r)*32 + l32];
    #pragma unroll
    for (int j = 0; j < NPW; j++) {
      const float4 a = *(const float4*)&shs[j*L_SLOT + L_D1 + i4];
      d2[j] = fmaf(a.x, wd[0], d2[j]);
      d2[j] = fmaf(a.y, wd[1], d2[j]);
      d2[j] = fmaf(a.z, wd[2], d2[j]);
      d2[j] = fmaf(a.w, wd[3], d2[j]);
    }
  }
  #pragma unroll
  for (int j = 0; j < NPW; j++) {
    d2[j] = fmaxf(d2[j], 0.f);
    if (lane < 32) shs[j*L_SLOT + L_D2 + lane] = d2[j];
  }

  float d3[NPW];
  const float d3b = bd2[lane];
  #pragma unroll
  for (int j = 0; j < NPW; j++) d3[j] = d3b;
  #pragma unroll
  for (int i4 = 0; i4 < 32; i4 += 4) {
    float wd[4];
    #pragma unroll
    for (int r = 0; r < 4; r++) wd[r] = Wd2[(i4+r)*64 + lane];
    #pragma unroll
    for (int j = 0; j < NPW; j++) {
      const float4 a = *(const float4*)&shs[j*L_SLOT + L_D2 + i4];
      d3[j] = fmaf(a.x, wd[0], d3[j]);
      d3[j] = fmaf(a.y, wd[1], d3[j]);
      d3[j] = fmaf(a.z, wd[2], d3[j]);
      d3[j] = fmaf(a.w, wd[3], d3[j]);
    }
  }
  const float wd3 = Wd3[lane];
  #pragma unroll
  for (int j = 0; j < NPW; j++) {
    float usp = fmaxf(d3[j], 0.f) * wd3;
    #pragma unroll
    for (int s2 = 32; s2 > 0; s2 >>= 1) usp += __shfl_xor(usp, s2);
    if (lane == 0) out[OUS + (nb+j)*TS + t] = usp + bd3[0];
  }
}

// ---------------------------------------------------------------------------
extern "C" void kernel_launch(void* const* d_in, const int* in_sizes, int n_in,
                              void* d_out, int out_size, void* d_ws, size_t ws_size,
                              hipStream_t stream) {
  const float* phi     = (const float*)d_in[0];
  const float* feat_dy = (const float*)d_in[1];
  const float* feat_st = (const float*)d_in[2];
  const float* Dv      = (const float*)d_in[3];
  const float* muv     = (const float*)d_in[4];
  const float* cv      = (const float*)d_in[5];
  const int*   adj4    = (const int*)d_in[6];
  const int*   adj25   = (const int*)d_in[7];
  const float* Wt0 = (const float*)d_in[8];
  const float* bt0 = (const float*)d_in[9];
  const float* Wt1 = (const float*)d_in[10];
  const float* bt1 = (const float*)d_in[11];
  const float* Wt2 = (const float*)d_in[12];
  const float* bt2 = (const float*)d_in[13];
  const float* Wq0 = (const float*)d_in[14];
  const float* bq0 = (const float*)d_in[15];
  const float* Wq1 = (const float*)d_in[16];
  const float* bq1 = (const float*)d_in[17];
  const float* Wq2 = (const float*)d_in[18];
  const float* bq2 = (const float*)d_in[19];
  const float* Wd0 = (const float*)d_in[20];
  const float* bd0 = (const float*)d_in[21];
  const float* Wd1 = (const float*)d_in[22];
  const float* bd1 = (const float*)d_in[23];
  const float* Wd2 = (const float*)d_in[24];
  const float* bd2 = (const float*)d_in[25];
  const float* Wd3 = (const float*)d_in[26];
  const float* bd3 = (const float*)d_in[27];

  float* ws  = (float*)d_ws;
  int*   wsi = (int*)(ws + O_FLTEND);
  float* out = (float*)d_out;

  k_setup_small<<<1, 256, 0, stream>>>(Dv, muv, cv, ws);
  k_setup_node<<<BN/4, 256, 0, stream>>>(phi, feat_dy, feat_st, adj4, adj25,
                                         Wt0, bt0, Wq0, bq0, Wd0, bd0, ws, wsi);
  k_build_rev<<<(BN*25 + 255)/256, 256, 0, stream>>>(adj25, wsi);

  float* fa = ws + O_FEATA; float* fb = ws + O_FEATB;
  float* aa = ws + O_AXYA;  float* ab = ws + O_AXYB;
  for (int t = 0; t < TS; t++) {
    k_step<<<BN/(NPW*4), 256, 0, stream>>>(ws, wsi, wsi + BN, t, fa, aa, fb, ab,
                                           adj4, adj25,
                                           Wt0, Wq0, Wt1, bt1, Wq1, bq1,
                                           Wt2, bt2, Wq2, bq2,
                                           Wd0, Wd1, bd1, Wd2, bd2, Wd3, bd3, out);
    float* tf = fa; fa = fb; fb = tf;
    float* ta = aa; aa = ab; ab = ta;
  }
}

// Round 3
// 2901.971 us; speedup vs baseline: 1.5971x; 1.5971x over previous
//
#include <hip/hip_runtime.h>
#include <math.h>

// ============================================================================
// ConflictNet: 30-step graph-PDE scan, B=2, N=8000, DY=12.
// Round 3: identical to round 2 EXCEPT __launch_bounds__(256,2) on k_step.
// Round 2's (256,4) capped VGPRs at 128; allocator picked 64 + full spill
// (WRITE_SIZE 10MB -> 256MB/step = scratch traffic). Cap 256 removes spills.
// ============================================================================

namespace {
constexpr int NB = 2;
constexpr int NN = 8000;
constexpr int BN = NB * NN;   // 16000
constexpr int TS = 30;
constexpr int CAP = 96;       // reverse-adjacency capacity
constexpr int NPW = 4;        // nodes per wave

// workspace float offsets
constexpr int O_COEFF = 0;              // 12x12 coeffM
constexpr int O_DIJ   = 144;            // 12
constexpr int O_MUIJ  = 156;            // 12
constexpr int O_MC    = 168;            // 12  (MUij @ coeffM)
constexpr int O_GPX   = 256;            // BN
constexpr int O_GPY   = O_GPX + BN;
constexpr int O_H1T   = O_GPY + BN;     // BN*64  trans layer-0 static (incl bias)
constexpr int O_H1Q   = O_H1T + BN*64;  // BN*64  q layer-0 static
constexpr int O_H1D   = O_H1Q + BN*64;  // BN*32  dec layer-0 static
constexpr int O_FEATA = O_H1D + BN*32;  // BN*12
constexpr int O_FEATB = O_FEATA + BN*12;
constexpr int O_AXYA  = O_FEATB + BN*12; // BN*24 (ax[12], ay[12])
constexpr int O_AXYB  = O_AXYA + BN*24;
constexpr int O_FLTEND= O_AXYB + BN*24;
// int region (after float region): rev counts [BN], rev entries [BN*CAP]

// output flat offsets
constexpr int OUS  = 0;                 // us   (B,N,1,T)
constexpr int OMIX = BN*TS;             // mix  (B,N,1,T)
constexpr int OQ0  = 2*BN*TS;           // q0_m (B,N,12,1,T)
constexpr int OFD  = OQ0 + BN*12*TS;    // fd   (B,N,1,T,12)

// LDS layout per node-slot (floats); all offsets multiple of 4 floats (16 B)
constexpr int L_AG   = 0;    // 24  (feat 0-11, wsum 12-23)
constexpr int L_H1   = 24;   // 128 (h1t 0-63, h1q 64-127)
constexpr int L_H2   = 152;  // 64  (h2t 0-31, h2q 32-63)
constexpr int L_NV   = 216;  // 16  (newv 0-11, pad)
constexpr int L_D1   = 232;  // 32
constexpr int L_D2   = 264;  // 32
constexpr int L_SLOT = 296;  // 1184 B per node
}

__device__ __forceinline__ float group5_sum(float v, int lane) {
  // lanes are (g, c) = (lane/12, lane%12), g<5 active; sum across the 5 groups.
  int g = lane / 12, c = lane % 12;
  float s1 = __shfl(v, c + 12*((g+1)%5));
  float s2 = __shfl(v, c + 12*((g+2)%5));
  float s3 = __shfl(v, c + 12*((g+3)%5));
  float s4 = __shfl(v, c + 12*((g+4)%5));
  return v + s1 + s2 + s3 + s4;
}

// ---------------------------------------------------------------------------
// S1: coeffM (12x12), Dij, MUij, MC = MUij @ coeffM
// ---------------------------------------------------------------------------
__global__ void k_setup_small(const float* __restrict__ D, const float* __restrict__ mu,
                              const float* __restrict__ cv, float* ws) {
  int t = threadIdx.x;
  for (int e = t; e < 144; e += 256) {
    int r = e / 12, q = e % 12;
    int rb = r >> 2, cb = q >> 2, ri = r & 3, qi = q & 3;
    float val = 0.f;
    if (rb == cb) {
      int f = ri*4 + qi;
      if (f % 5 == 0) val = 1.f;
      else val = cv[64 + rb*12 + (f/5)*4 + (f%5) - 1];
    } else if (rb == 0 && cb == 2) val = cv[     ri*4 + qi];
    else if   (rb == 1 && cb == 2) val = cv[16 + ri*4 + qi];
    else if   (rb == 2 && cb == 0) val = cv[32 + ri*4 + qi];
    else if   (rb == 2 && cb == 1) val = cv[48 + ri*4 + qi];
    ws[O_COEFF + e] = fmaxf(val, 0.f);
  }
  if (t < 12) {
    ws[O_DIJ + t]  = (t < 4) ? 0.f : fmaxf(D[t-4], 0.f);
    ws[O_MUIJ + t] = (t < 4) ? fmaxf(mu[t], 0.f) : ((t < 8) ? 0.f : fmaxf(mu[t-4], 0.f));
  }
  __syncthreads();
  if (t < 12) {
    float acc = 0.f;
    for (int c = 0; c < 12; c++) acc += ws[O_MUIJ + c] * ws[O_COEFF + c*12 + t];
    ws[O_MC + t] = acc;
  }
}

// ---------------------------------------------------------------------------
// S2: per-node invariants (wave per node; runs once)
// ---------------------------------------------------------------------------
__global__ __launch_bounds__(256) void k_setup_node(
    const float* __restrict__ phi, const float* __restrict__ feat_dy,
    const float* __restrict__ feat_st,
    const int* __restrict__ adj4, const int* __restrict__ adj25,
    const float* __restrict__ Wt0, const float* __restrict__ bt0,
    const float* __restrict__ Wq0, const float* __restrict__ bq0,
    const float* __restrict__ Wd0, const float* __restrict__ bd0,
    float* ws, int* wsi) {
  const int wid  = (blockIdx.x * blockDim.x + threadIdx.x) >> 6;
  const int lane = threadIdx.x & 63;
  if (wid >= BN) return;
  const int b = wid / NN, n = wid % NN;

  const int* a4 = adj4 + n*4;
  const float gpx = phi[b*NN + a4[1]] - phi[b*NN + a4[0]];
  const float gpy = phi[b*NN + a4[3]] - phi[b*NN + a4[2]];
  if (lane == 0) { ws[O_GPX + wid] = gpx; ws[O_GPY + wid] = gpy; wsi[wid] = 0; }

  int idx = 0; float w = 0.f;
  if (lane < 25) { idx = adj25[n*25 + lane]; w = (lane == 0) ? 1.f : 0.01f; }
  float phiw = (lane < 25) ? w * phi[b*NN + idx] : 0.f;
  #pragma unroll
  for (int s = 32; s > 0; s >>= 1) phiw += __shfl_xor(phiw, s);

  float stv[6], stw[6];
  #pragma unroll
  for (int j = 0; j < 6; j++) {
    float x = (lane < 25) ? w * feat_st[(b*NN + idx)*6 + j] : 0.f;
    #pragma unroll
    for (int s = 32; s > 0; s >>= 1) x += __shfl_xor(x, s);
    stw[j] = x;
    stv[j] = feat_st[(b*NN + n)*6 + j];
  }
  const float phiv = phi[b*NN + n];

  float hT = bt0[lane] + phiv*Wt0[24*64 + lane] + phiw*Wt0[25*64 + lane];
  float hQ = bq0[lane] + phiv*Wq0[24*64 + lane] + phiw*Wq0[25*64 + lane];
  #pragma unroll
  for (int i = 0; i < 12; i++) {
    hT = fmaf(ws[O_DIJ  + i], Wt0[(26+i)*64 + lane], hT);
    hT = fmaf(ws[O_MUIJ + i], Wt0[(38+i)*64 + lane], hT);
  }
  #pragma unroll
  for (int j = 0; j < 6; j++) {
    hT = fmaf(stv[j], Wt0[(50+j)*64 + lane], hT);
    hT = fmaf(stw[j], Wt0[(56+j)*64 + lane], hT);
    hQ = fmaf(stv[j], Wq0[(26+j)*64 + lane], hQ);
    hQ = fmaf(stw[j], Wq0[(32+j)*64 + lane], hQ);
  }
  ws[O_H1T + wid*64 + lane] = hT;
  ws[O_H1Q + wid*64 + lane] = hQ;
  if (lane < 32) {
    float hD = bd0[lane];
    #pragma unroll
    for (int j = 0; j < 6; j++) hD = fmaf(stv[j], Wd0[(12+j)*32 + lane], hD);
    ws[O_H1D + wid*32 + lane] = hD;
  }
  if (lane < 12) {
    float f = feat_dy[wid*12 + lane];
    ws[O_FEATA + wid*12 + lane] = f;
    float mass = (f == 0.f) ? 1.f : f;
    float mc = ws[O_MC + lane];
    ws[O_AXYA + wid*24 + lane]      = fminf(fmaxf(gpx*mc/mass, -2.f), 2.f);
    ws[O_AXYA + wid*24 + 12 + lane] = fminf(fmaxf(gpy*mc/mass, -2.f), 2.f);
  }
}

// ---------------------------------------------------------------------------
// S3: build reverse adjacency for the scatter (per batch).
// ---------------------------------------------------------------------------
__global__ void k_build_rev(const int* __restrict__ adj25, int* wsi) {
  int i = blockIdx.x * blockDim.x + threadIdx.x;
  if (i >= BN * 25) return;
  int b = i / (NN * 25);
  int rem = i % (NN * 25);
  int m = rem / 25, k = rem % 25;
  int tgt = adj25[i];
  int slot = atomicAdd(&wsi[b*NN + tgt], 1);
  if (slot < CAP) wsi[BN + (b*NN + tgt)*CAP + slot] = (m << 5) | k;
}

// ---------------------------------------------------------------------------
// Step kernel: one scan iteration.  4 nodes per wave, LDS act broadcast.
// __launch_bounds__(256,2): VGPR cap 256 -> no scratch spill (round-2 lesson).
// ---------------------------------------------------------------------------
__global__ __launch_bounds__(256, 2) void k_step(
    const float* __restrict__ ws, const int* __restrict__ rcnt,
    const int* __restrict__ rent, int t,
    const float* __restrict__ fsrc, const float* __restrict__ axsrc,
    float* __restrict__ fdst, float* __restrict__ axdst,
    const int* __restrict__ adj4, const int* __restrict__ adj25,
    const float* __restrict__ Wt0, const float* __restrict__ Wq0,
    const float* __restrict__ Wt1, const float* __restrict__ bt1,
    const float* __restrict__ Wq1, const float* __restrict__ bq1,
    const float* __restrict__ Wt2, const float* __restrict__ bt2,
    const float* __restrict__ Wq2, const float* __restrict__ bq2,
    const float* __restrict__ Wd0, const float* __restrict__ Wd1,
    const float* __restrict__ bd1, const float* __restrict__ Wd2,
    const float* __restrict__ bd2, const float* __restrict__ Wd3,
    const float* __restrict__ bd3, float* __restrict__ out) {
  __shared__ __attribute__((aligned(16))) float sh[4 * NPW * L_SLOT];
  const int wslot = threadIdx.x >> 6;
  const int lane  = threadIdx.x & 63;
  const int wid   = blockIdx.x * 4 + wslot;   // wave id, 0..3999
  const int nb    = wid * NPW;                // base node (all 4 in same batch)
  const int b  = nb / NN;
  const int n0 = nb % NN;
  const int c12 = lane % 12;
  const int g   = lane / 12;
  float* shs = sh + wslot * (NPW * L_SLOT);

  const float dij  = ws[O_DIJ  + c12];
  const float muij = ws[O_MUIJ + c12];
  float cfv[12];
  #pragma unroll
  for (int cc = 0; cc < 12; cc++) cfv[cc] = ws[O_COEFF + cc*12 + c12];

  // ---- feat + 25-neighbor weighted aggregate ----
  float f_c[NPW];
  #pragma unroll
  for (int j = 0; j < NPW; j++) {
    const int n = n0 + j;
    f_c[j] = fsrc[(b*NN + n)*12 + c12];
    float agw = 0.f;
    if (g < 5) {
      const int* a0 = adj25 + n*25;
      #pragma unroll
      for (int kk = 0; kk < 5; kk++) {
        int k = g + 5*kk;
        float wgt = (k == 0) ? 1.f : 0.01f;
        agw = fmaf(wgt, fsrc[(b*NN + a0[k])*12 + c12], agw);
      }
    }
    agw = group5_sum(agw, lane);
    float AG = (lane < 12) ? f_c[j] : agw;
    if (lane < 24) shs[j*L_SLOT + L_AG + lane] = AG;
  }

  // ---- stencil: J, Fdiv, v; udiff = v @ coeffM ----
  float udiff[NPW];
  {
    float vsv[NPW];
    #pragma unroll
    for (int j = 0; j < NPW; j++) {
      const int n = n0 + j;
      const int* a4p = adj4 + n*4;
      const int m0 = a4p[0], m1 = a4p[1], m2 = a4p[2], m3 = a4p[3];
      const float f0 = fsrc[(b*NN+m0)*12 + c12];
      const float f1 = fsrc[(b*NN+m1)*12 + c12];
      const float f2 = fsrc[(b*NN+m2)*12 + c12];
      const float f3 = fsrc[(b*NN+m3)*12 + c12];
      const float J = 4.f * ((f0+f1+f2+f3) - 4.f*f_c[j]);
      const float gx0 = ws[O_GPX + b*NN + m0], gx1 = ws[O_GPX + b*NN + m1];
      const float gy2 = ws[O_GPY + b*NN + m2], gy3 = ws[O_GPY + b*NN + m3];
      const float Fdiv = gx1*f1 - gx0*f0 + gy3*f3 - gy2*f2;
      vsv[j] = dij*J - muij*Fdiv;
    }
    #pragma unroll
    for (int j = 0; j < NPW; j++) {
      float acc = 0.f;
      #pragma unroll
      for (int cc = 0; cc < 12; cc++) acc = fmaf(__shfl(vsv[j], cc), cfv[cc], acc);
      udiff[j] = acc;
    }
  }

  // ---- u_rig via reverse-adjacency gather ----
  float urig[NPW];
  #pragma unroll
  for (int j = 0; j < NPW; j++) {
    const int wnode = nb + j;
    int cnt = rcnt[wnode]; if (cnt > CAP) cnt = CAP;
    const int* re = rent + wnode*CAP;
    float usc = 0.f;
    if (g < 5) {
      for (int e = g; e < cnt; e += 5) {
        int pk = re[e];
        int m = pk >> 5, k = pk & 31;
        float kx = (float)(k - (k/5)*5);
        float ky = (float)(k/5);
        int base = b*NN + m;
        float fm = fsrc[base*12 + c12];
        float ax = axsrc[base*24 + c12];
        float ay = axsrc[base*24 + 12 + c12];
        float px = fmaxf(1.f - fabsf(ax - kx), 0.f);
        float py = fmaxf(1.f - fabsf(ay - ky), 0.f);
        usc = fmaf(px*py, fm, usc);
      }
    }
    usc = group5_sum(usc, lane);
    urig[j] = usc - f_c[j];
  }

  // ---- trans & q hidden-1 (static part precomputed; 24 dynamic rows) ----
  float h1t[NPW], h1q[NPW];
  #pragma unroll
  for (int j = 0; j < NPW; j++) {
    h1t[j] = ws[O_H1T + (nb+j)*64 + lane];
    h1q[j] = ws[O_H1Q + (nb+j)*64 + lane];
  }
  #pragma unroll
  for (int i4 = 0; i4 < 24; i4 += 4) {
    float wt[4], wq[4];
    #pragma unroll
    for (int r = 0; r < 4; r++) {
      wt[r] = Wt0[(i4+r)*64 + lane];
      wq[r] = Wq0[(i4+r)*64 + lane];
    }
    #pragma unroll
    for (int j = 0; j < NPW; j++) {
      const float4 a = *(const float4*)&shs[j*L_SLOT + L_AG + i4];
      h1t[j] = fmaf(a.x, wt[0], h1t[j]); h1q[j] = fmaf(a.x, wq[0], h1q[j]);
      h1t[j] = fmaf(a.y, wt[1], h1t[j]); h1q[j] = fmaf(a.y, wq[1], h1q[j]);
      h1t[j] = fmaf(a.z, wt[2], h1t[j]); h1q[j] = fmaf(a.z, wq[2], h1q[j]);
      h1t[j] = fmaf(a.w, wt[3], h1t[j]); h1q[j] = fmaf(a.w, wq[3], h1q[j]);
    }
  }
  #pragma unroll
  for (int j = 0; j < NPW; j++) {
    shs[j*L_SLOT + L_H1 + lane]      = fmaxf(h1t[j], 0.f);
    shs[j*L_SLOT + L_H1 + 64 + lane] = fmaxf(h1q[j], 0.f);
  }

  // ---- hidden-2: lanes 0-31 trans, 32-63 q; acts broadcast from LDS ----
  const int l32 = lane & 31;
  const bool isQ = lane >= 32;
  const float* W1p = (isQ ? Wq1 : Wt1) + l32;
  const int hoff = isQ ? 64 : 0;
  const float h2b = isQ ? bq1[l32] : bt1[l32];
  float h2[NPW];
  #pragma unroll
  for (int j = 0; j < NPW; j++) h2[j] = h2b;
  #pragma unroll
  for (int i4 = 0; i4 < 64; i4 += 4) {
    float w1[4];
    #pragma unroll
    for (int r = 0; r < 4; r++) w1[r] = W1p[(i4+r)*32];
    #pragma unroll
    for (int j = 0; j < NPW; j++) {
      const float4 a = *(const float4*)&shs[j*L_SLOT + L_H1 + hoff + i4];
      h2[j] = fmaf(a.x, w1[0], h2[j]);
      h2[j] = fmaf(a.y, w1[1], h2[j]);
      h2[j] = fmaf(a.z, w1[2], h2[j]);
      h2[j] = fmaf(a.w, w1[3], h2[j]);
    }
  }
  #pragma unroll
  for (int j = 0; j < NPW; j++)
    shs[j*L_SLOT + L_H2 + lane] = fmaxf(h2[j], 0.f);

  // ---- mix logit (col 25 of Wt2) + q0 (channel c12 per lane) ----
  float mixz[NPW], q0[NPW];
  const float* Wq2p = Wq2 + c12;
  const float mzb = bt2[25];
  const float q0b = bq2[c12];
  #pragma unroll
  for (int j = 0; j < NPW; j++) { mixz[j] = mzb; q0[j] = q0b; }
  #pragma unroll
  for (int i4 = 0; i4 < 32; i4 += 4) {
    float wz[4], wq[4];
    #pragma unroll
    for (int r = 0; r < 4; r++) {
      wz[r] = Wt2[(i4+r)*26 + 25];   // uniform -> scalar load
      wq[r] = Wq2p[(i4+r)*12];
    }
    #pragma unroll
    for (int j = 0; j < NPW; j++) {
      const float4 at = *(const float4*)&shs[j*L_SLOT + L_H2 + i4];
      const float4 aq = *(const float4*)&shs[j*L_SLOT + L_H2 + 32 + i4];
      mixz[j] = fmaf(at.x, wz[0], mixz[j]); q0[j] = fmaf(aq.x, wq[0], q0[j]);
      mixz[j] = fmaf(at.y, wz[1], mixz[j]); q0[j] = fmaf(aq.y, wq[1], q0[j]);
      mixz[j] = fmaf(at.z, wz[2], mixz[j]); q0[j] = fmaf(aq.z, wq[2], q0[j]);
      mixz[j] = fmaf(at.w, wz[3], mixz[j]); q0[j] = fmaf(aq.w, wq[3], q0[j]);
    }
  }

  // ---- update, outputs, next-step ax/ay ----
  float newv[NPW];
  #pragma unroll
  for (int j = 0; j < NPW; j++) {
    const int bn = nb + j;
    const float mix = 1.f / (1.f + expf(-mixz[j]));
    newv[j] = f_c[j] + mix*udiff[j] + (1.f - mix)*urig[j] + q0[j];
    if (lane < 12) {
      shs[j*L_SLOT + L_NV + lane] = newv[j];
      out[OQ0 + (bn*12 + lane)*TS + t] = q0[j];
      out[OFD + (bn*TS + t)*12 + lane] = newv[j];
      fdst[bn*12 + lane] = newv[j];
      float mass = (newv[j] == 0.f) ? 1.f : newv[j];
      float mc = ws[O_MC + lane];
      float gpxn = ws[O_GPX + bn], gpyn = ws[O_GPY + bn];
      axdst[bn*24 + lane]      = fminf(fmaxf(gpxn*mc/mass, -2.f), 2.f);
      axdst[bn*24 + 12 + lane] = fminf(fmaxf(gpyn*mc/mass, -2.f), 2.f);
    }
    if (lane == 0) out[OMIX + bn*TS + t] = mix;
  }

  // ---- dec MLP: 12(+static) -> 32 -> 32 -> 64 -> 1 ----
  float d1[NPW];
  #pragma unroll
  for (int j = 0; j < NPW; j++) d1[j] = ws[O_H1D + (nb+j)*32 + l32];
  #pragma unroll
  for (int i4 = 0; i4 < 12; i4 += 4) {
    float wd[4];
    #pragma unroll
    for (int r = 0; r < 4; r++) wd[r] = Wd0[(i4+r)*32 + l32];
    #pragma unroll
    for (int j = 0; j < NPW; j++) {
      const float4 a = *(const float4*)&shs[j*L_SLOT + L_NV + i4];
      d1[j] = fmaf(a.x, wd[0], d1[j]);
      d1[j] = fmaf(a.y, wd[1], d1[j]);
      d1[j] = fmaf(a.z, wd[2], d1[j]);
      d1[j] = fmaf(a.w, wd[3], d1[j]);
    }
  }
  #pragma unroll
  for (int j = 0; j < NPW; j++) {
    d1[j] = fmaxf(d1[j], 0.f);
    if (lane < 32) shs[j*L_SLOT + L_D1 + lane] = d1[j];
  }

  float d2[NPW];
  const float d2b = bd1[l32];
  #pragma unroll
  for (int j = 0; j < NPW; j++) d2[j] = d2b;
  #pragma unroll
  for (int i4 = 0; i4 < 32; i4 += 4) {
    float wd[4];
    #pragma unroll
    for (int r = 0; r < 4; r++) wd[r] = Wd1[(i4+r)*32 + l32];
    #pragma unroll
    for (int j = 0; j < NPW; j++) {
      const float4 a = *(const float4*)&shs[j*L_SLOT + L_D1 + i4];
      d2[j] = fmaf(a.x, wd[0], d2[j]);
      d2[j] = fmaf(a.y, wd[1], d2[j]);
      d2[j] = fmaf(a.z, wd[2], d2[j]);
      d2[j] = fmaf(a.w, wd[3], d2[j]);
    }
  }
  #pragma unroll
  for (int j = 0; j < NPW; j++) {
    d2[j] = fmaxf(d2[j], 0.f);
    if (lane < 32) shs[j*L_SLOT + L_D2 + lane] = d2[j];
  }

  float d3[NPW];
  const float d3b = bd2[lane];
  #pragma unroll
  for (int j = 0; j < NPW; j++) d3[j] = d3b;
  #pragma unroll
  for (int i4 = 0; i4 < 32; i4 += 4) {
    float wd[4];
    #pragma unroll
    for (int r = 0; r < 4; r++) wd[r] = Wd2[(i4+r)*64 + lane];
    #pragma unroll
    for (int j = 0; j < NPW; j++) {
      const float4 a = *(const float4*)&shs[j*L_SLOT + L_D2 + i4];
      d3[j] = fmaf(a.x, wd[0], d3[j]);
      d3[j] = fmaf(a.y, wd[1], d3[j]);
      d3[j] = fmaf(a.z, wd[2], d3[j]);
      d3[j] = fmaf(a.w, wd[3], d3[j]);
    }
  }
  const float wd3 = Wd3[lane];
  #pragma unroll
  for (int j = 0; j < NPW; j++) {
    float usp = fmaxf(d3[j], 0.f) * wd3;
    #pragma unroll
    for (int s2 = 32; s2 > 0; s2 >>= 1) usp += __shfl_xor(usp, s2);
    if (lane == 0) out[OUS + (nb+j)*TS + t] = usp + bd3[0];
  }
}

// ---------------------------------------------------------------------------
extern "C" void kernel_launch(void* const* d_in, const int* in_sizes, int n_in,
                              void* d_out, int out_size, void* d_ws, size_t ws_size,
                              hipStream_t stream) {
  const float* phi     = (const float*)d_in[0];
  const float* feat_dy = (const float*)d_in[1];
  const float* feat_st = (const float*)d_in[2];
  const float* Dv      = (const float*)d_in[3];
  const float* muv     = (const float*)d_in[4];
  const float* cv      = (const float*)d_in[5];
  const int*   adj4    = (const int*)d_in[6];
  const int*   adj25   = (const int*)d_in[7];
  const float* Wt0 = (const float*)d_in[8];
  const float* bt0 = (const float*)d_in[9];
  const float* Wt1 = (const float*)d_in[10];
  const float* bt1 = (const float*)d_in[11];
  const float* Wt2 = (const float*)d_in[12];
  const float* bt2 = (const float*)d_in[13];
  const float* Wq0 = (const float*)d_in[14];
  const float* bq0 = (const float*)d_in[15];
  const float* Wq1 = (const float*)d_in[16];
  const float* bq1 = (const float*)d_in[17];
  const float* Wq2 = (const float*)d_in[18];
  const float* bq2 = (const float*)d_in[19];
  const float* Wd0 = (const float*)d_in[20];
  const float* bd0 = (const float*)d_in[21];
  const float* Wd1 = (const float*)d_in[22];
  const float* bd1 = (const float*)d_in[23];
  const float* Wd2 = (const float*)d_in[24];
  const float* bd2 = (const float*)d_in[25];
  const float* Wd3 = (const float*)d_in[26];
  const float* bd3 = (const float*)d_in[27];

  float* ws  = (float*)d_ws;
  int*   wsi = (int*)(ws + O_FLTEND);
  float* out = (float*)d_out;

  k_setup_small<<<1, 256, 0, stream>>>(Dv, muv, cv, ws);
  k_setup_node<<<BN/4, 256, 0, stream>>>(phi, feat_dy, feat_st, adj4, adj25,
                                         Wt0, bt0, Wq0, bq0, Wd0, bd0, ws, wsi);
  k_build_rev<<<(BN*25 + 255)/256, 256, 0, stream>>>(adj25, wsi);

  float* fa = ws + O_FEATA; float* fb = ws + O_FEATB;
  float* aa = ws + O_AXYA;  float* ab = ws + O_AXYB;
  for (int t = 0; t < TS; t++) {
    k_step<<<BN/(NPW*4), 256, 0, stream>>>(ws, wsi, wsi + BN, t, fa, aa, fb, ab,
                                           adj4, adj25,
                                           Wt0, Wq0, Wt1, bt1, Wq1, bq1,
                                           Wt2, bt2, Wq2, bq2,
                                           Wd0, Wd1, bd1, Wd2, bd2, Wd3, bd3, out);
    float* tf = fa; fa = fb; fb = tf;
    float* ta = aa; aa = ab; ab = ta;
  }
}

// Round 4
// 2697.416 us; speedup vs baseline: 1.7182x; 1.0758x over previous
//
#include <hip/hip_runtime.h>
#include <math.h>

// ============================================================================
// ConflictNet: 30-step graph-PDE scan, B=2, N=8000, DY=12.
// Round 4: back to NPW=1 wave-per-node (round-1 structure, no spill) +
//  - weights TRANSPOSED once into ws -> per-lane contiguous rows, float4 loads
//  - LDS float4 activation broadcast (uniform ds_read_b128) replaces shfl chains
//  - coeffM transposed for udiff
// Rounds 2/3 lesson: the x4-node unroll makes the compiler hoist huge load
// batches and spill (~107MB/step scratch). Keep the body small instead.
// ============================================================================

namespace {
constexpr int NB = 2;
constexpr int NN = 8000;
constexpr int BN = NB * NN;   // 16000
constexpr int TS = 30;
constexpr int CAP = 96;       // reverse-adjacency capacity

// ---- workspace float offsets ----
constexpr int O_COEFF = 0;                    // 144: coeffM row-major [r*12+c]
constexpr int O_CFT   = O_COEFF + 144;        // 144: coeffM^T [c*12+r]
constexpr int O_DIJ   = O_CFT + 144;          // 12
constexpr int O_MUIJ  = O_DIJ + 12;           // 12
constexpr int O_MC    = O_MUIJ + 12;          // 12
constexpr int O_WT0T  = 336;                  // [64][24] Wt0 dyn cols transposed
constexpr int O_WQ0T  = O_WT0T + 1536;        // [64][24]
constexpr int O_WT1T  = O_WQ0T + 1536;        // [32][64]
constexpr int O_WQ1T  = O_WT1T + 2048;        // [32][64]
constexpr int O_WQ2T  = O_WQ1T + 2048;        // [12][32]
constexpr int O_WZ    = O_WQ2T + 384;         // [32]  Wt2[:,25]
constexpr int O_WD0T  = O_WZ + 32;            // [32][12]
constexpr int O_WD1T  = O_WD0T + 384;         // [32][32]
constexpr int O_WD2T  = O_WD1T + 1024;        // [64][32]
constexpr int O_GPX   = O_WD2T + 2048;        // BN
constexpr int O_GPY   = O_GPX + BN;
constexpr int O_H1T   = O_GPY + BN;           // BN*64
constexpr int O_H1Q   = O_H1T + BN*64;        // BN*64
constexpr int O_H1D   = O_H1Q + BN*64;        // BN*32
constexpr int O_FEATA = O_H1D + BN*32;        // BN*12
constexpr int O_FEATB = O_FEATA + BN*12;
constexpr int O_AXYA  = O_FEATB + BN*12;      // BN*24
constexpr int O_AXYB  = O_AXYA + BN*24;
constexpr int O_FLTEND= O_AXYB + BN*24;
// int region after floats: rev counts [BN], rev entries [BN*CAP]

// ---- output flat offsets ----
constexpr int OUS  = 0;
constexpr int OMIX = BN*TS;
constexpr int OQ0  = 2*BN*TS;
constexpr int OFD  = OQ0 + BN*12*TS;

// ---- per-wave LDS slot (floats), 16B-aligned sub-offsets ----
constexpr int L_AG   = 0;    // 24
constexpr int L_H1   = 24;   // 128 (h1t 0-63 | h1q 64-127)
constexpr int L_H2   = 152;  // 64  (h2t 0-31 | h2q 32-63)
constexpr int L_NV   = 216;  // 12 (+4 pad)
constexpr int L_D1   = 232;  // 32
constexpr int L_D2   = 264;  // 32
constexpr int L_SLOT = 296;
}

__device__ __forceinline__ float group5_sum(float v, int lane) {
  int g = lane / 12, c = lane % 12;
  float s1 = __shfl(v, c + 12*((g+1)%5));
  float s2 = __shfl(v, c + 12*((g+2)%5));
  float s3 = __shfl(v, c + 12*((g+3)%5));
  float s4 = __shfl(v, c + 12*((g+4)%5));
  return v + s1 + s2 + s3 + s4;
}

// ---------------------------------------------------------------------------
// S1: coeffM (+transpose), Dij, MUij, MC
// ---------------------------------------------------------------------------
__global__ void k_setup_small(const float* __restrict__ D, const float* __restrict__ mu,
                              const float* __restrict__ cv, float* ws) {
  int t = threadIdx.x;
  for (int e = t; e < 144; e += 256) {
    int r = e / 12, q = e % 12;
    int rb = r >> 2, cb = q >> 2, ri = r & 3, qi = q & 3;
    float val = 0.f;
    if (rb == cb) {
      int f = ri*4 + qi;
      if (f % 5 == 0) val = 1.f;
      else val = cv[64 + rb*12 + (f/5)*4 + (f%5) - 1];
    } else if (rb == 0 && cb == 2) val = cv[     ri*4 + qi];
    else if   (rb == 1 && cb == 2) val = cv[16 + ri*4 + qi];
    else if   (rb == 2 && cb == 0) val = cv[32 + ri*4 + qi];
    else if   (rb == 2 && cb == 1) val = cv[48 + ri*4 + qi];
    ws[O_COEFF + e] = fmaxf(val, 0.f);
  }
  if (t < 12) {
    ws[O_DIJ + t]  = (t < 4) ? 0.f : fmaxf(D[t-4], 0.f);
    ws[O_MUIJ + t] = (t < 4) ? fmaxf(mu[t], 0.f) : ((t < 8) ? 0.f : fmaxf(mu[t-4], 0.f));
  }
  __syncthreads();
  if (t < 144) {                                // CFT[c*12+r] = COEFF[r*12+c]
    int r = t / 12, c = t % 12;
    ws[O_CFT + c*12 + r] = ws[O_COEFF + t];
  }
  if (t < 12) {
    float acc = 0.f;
    for (int c = 0; c < 12; c++) acc += ws[O_MUIJ + c] * ws[O_COEFF + c*12 + t];
    ws[O_MC + t] = acc;
  }
}

// ---------------------------------------------------------------------------
// S1b: transpose weight matrices into ws (per-lane contiguous rows)
// ---------------------------------------------------------------------------
__global__ void k_xpose(const float* __restrict__ Wt0, const float* __restrict__ Wq0,
                        const float* __restrict__ Wt1, const float* __restrict__ Wq1,
                        const float* __restrict__ Wt2, const float* __restrict__ Wq2,
                        const float* __restrict__ Wd0, const float* __restrict__ Wd1,
                        const float* __restrict__ Wd2, float* ws) {
  const int t = blockIdx.x * blockDim.x + threadIdx.x;
  const int G = gridDim.x * blockDim.x;
  for (int e = t; e < 1536; e += G) {           // [64][24] <- rows 0..23 of 62x64
    int l = e / 24, i = e % 24;
    ws[O_WT0T + e] = Wt0[i*64 + l];
    ws[O_WQ0T + e] = Wq0[i*64 + l];
  }
  for (int e = t; e < 2048; e += G) {           // [32][64] <- 64x32
    int l = e / 64, i = e % 64;
    ws[O_WT1T + e] = Wt1[i*32 + l];
    ws[O_WQ1T + e] = Wq1[i*32 + l];
  }
  for (int e = t; e < 384; e += G) {            // [12][32] <- 32x12
    int c = e / 32, i = e % 32;
    ws[O_WQ2T + e] = Wq2[i*12 + c];
  }
  for (int e = t; e < 32; e += G) ws[O_WZ + e] = Wt2[e*26 + 25];
  for (int e = t; e < 384; e += G) {            // [32][12] <- rows 0..11 of 18x32
    int l = e / 12, i = e % 12;
    ws[O_WD0T + e] = Wd0[i*32 + l];
  }
  for (int e = t; e < 1024; e += G) {           // [32][32]
    int l = e / 32, i = e % 32;
    ws[O_WD1T + e] = Wd1[i*32 + l];
  }
  for (int e = t; e < 2048; e += G) {           // [64][32] <- 32x64
    int l = e / 32, i = e % 32;
    ws[O_WD2T + e] = Wd2[i*64 + l];
  }
}

// ---------------------------------------------------------------------------
// S2: per-node invariants (wave per node; runs once)
// ---------------------------------------------------------------------------
__global__ __launch_bounds__(256) void k_setup_node(
    const float* __restrict__ phi, const float* __restrict__ feat_dy,
    const float* __restrict__ feat_st,
    const int* __restrict__ adj4, const int* __restrict__ adj25,
    const float* __restrict__ Wt0, const float* __restrict__ bt0,
    const float* __restrict__ Wq0, const float* __restrict__ bq0,
    const float* __restrict__ Wd0, const float* __restrict__ bd0,
    float* ws, int* wsi) {
  const int wid  = (blockIdx.x * blockDim.x + threadIdx.x) >> 6;
  const int lane = threadIdx.x & 63;
  if (wid >= BN) return;
  const int b = wid / NN, n = wid % NN;

  const int* a4 = adj4 + n*4;
  const float gpx = phi[b*NN + a4[1]] - phi[b*NN + a4[0]];
  const float gpy = phi[b*NN + a4[3]] - phi[b*NN + a4[2]];
  if (lane == 0) { ws[O_GPX + wid] = gpx; ws[O_GPY + wid] = gpy; wsi[wid] = 0; }

  int idx = 0; float w = 0.f;
  if (lane < 25) { idx = adj25[n*25 + lane]; w = (lane == 0) ? 1.f : 0.01f; }
  float phiw = (lane < 25) ? w * phi[b*NN + idx] : 0.f;
  #pragma unroll
  for (int s = 32; s > 0; s >>= 1) phiw += __shfl_xor(phiw, s);

  float stv[6], stw[6];
  #pragma unroll
  for (int j = 0; j < 6; j++) {
    float x = (lane < 25) ? w * feat_st[(b*NN + idx)*6 + j] : 0.f;
    #pragma unroll
    for (int s = 32; s > 0; s >>= 1) x += __shfl_xor(x, s);
    stw[j] = x;
    stv[j] = feat_st[(b*NN + n)*6 + j];
  }
  const float phiv = phi[b*NN + n];

  float hT = bt0[lane] + phiv*Wt0[24*64 + lane] + phiw*Wt0[25*64 + lane];
  float hQ = bq0[lane] + phiv*Wq0[24*64 + lane] + phiw*Wq0[25*64 + lane];
  #pragma unroll
  for (int i = 0; i < 12; i++) {
    hT = fmaf(ws[O_DIJ  + i], Wt0[(26+i)*64 + lane], hT);
    hT = fmaf(ws[O_MUIJ + i], Wt0[(38+i)*64 + lane], hT);
  }
  #pragma unroll
  for (int j = 0; j < 6; j++) {
    hT = fmaf(stv[j], Wt0[(50+j)*64 + lane], hT);
    hT = fmaf(stw[j], Wt0[(56+j)*64 + lane], hT);
    hQ = fmaf(stv[j], Wq0[(26+j)*64 + lane], hQ);
    hQ = fmaf(stw[j], Wq0[(32+j)*64 + lane], hQ);
  }
  ws[O_H1T + wid*64 + lane] = hT;
  ws[O_H1Q + wid*64 + lane] = hQ;
  if (lane < 32) {
    float hD = bd0[lane];
    #pragma unroll
    for (int j = 0; j < 6; j++) hD = fmaf(stv[j], Wd0[(12+j)*32 + lane], hD);
    ws[O_H1D + wid*32 + lane] = hD;
  }
  if (lane < 12) {
    float f = feat_dy[wid*12 + lane];
    ws[O_FEATA + wid*12 + lane] = f;
    float mass = (f == 0.f) ? 1.f : f;
    float mc = ws[O_MC + lane];
    ws[O_AXYA + wid*24 + lane]      = fminf(fmaxf(gpx*mc/mass, -2.f), 2.f);
    ws[O_AXYA + wid*24 + 12 + lane] = fminf(fmaxf(gpy*mc/mass, -2.f), 2.f);
  }
}

// ---------------------------------------------------------------------------
// S3: build reverse adjacency for the scatter (per batch).
// ---------------------------------------------------------------------------
__global__ void k_build_rev(const int* __restrict__ adj25, int* wsi) {
  int i = blockIdx.x * blockDim.x + threadIdx.x;
  if (i >= BN * 25) return;
  int b = i / (NN * 25);
  int rem = i % (NN * 25);
  int m = rem / 25, k = rem % 25;
  int tgt = adj25[i];
  int slot = atomicAdd(&wsi[b*NN + tgt], 1);
  if (slot < CAP) wsi[BN + (b*NN + tgt)*CAP + slot] = (m << 5) | k;
}

// ---------------------------------------------------------------------------
// Step kernel: one scan iteration.  Wave per node; transposed-f4 weights,
// LDS f4 activation broadcast.  No multi-node unroll (spill lesson R2/R3).
// ---------------------------------------------------------------------------
__global__ __launch_bounds__(256) void k_step(
    const float* __restrict__ ws, const int* __restrict__ rcnt,
    const int* __restrict__ rent, int t,
    const float* __restrict__ fsrc, const float* __restrict__ axsrc,
    float* __restrict__ fdst, float* __restrict__ axdst,
    const int* __restrict__ adj4, const int* __restrict__ adj25,
    const float* __restrict__ bt1, const float* __restrict__ bq1,
    const float* __restrict__ bt2, const float* __restrict__ bq2,
    const float* __restrict__ bd1, const float* __restrict__ bd2,
    const float* __restrict__ Wd3, const float* __restrict__ bd3,
    float* __restrict__ out) {
  __shared__ __attribute__((aligned(16))) float sh[4 * L_SLOT];
  const int wslot = threadIdx.x >> 6;
  const int lane  = threadIdx.x & 63;
  const int wid   = blockIdx.x * 4 + wslot;
  const int b  = wid / NN;
  const int n  = wid % NN;
  const int c12 = lane % 12;
  const int g   = lane / 12;
  float* shs = sh + wslot * L_SLOT;

  const float f_c = fsrc[wid*12 + c12];

  // ---- 25-neighbor weighted aggregate ----
  {
    float agw = 0.f;
    if (g < 5) {
      const int* a0 = adj25 + n*25;
      #pragma unroll
      for (int kk = 0; kk < 5; kk++) {
        int k = g + 5*kk;
        float wgt = (k == 0) ? 1.f : 0.01f;
        agw = fmaf(wgt, fsrc[(b*NN + a0[k])*12 + c12], agw);
      }
    }
    agw = group5_sum(agw, lane);
    if (lane < 24) shs[L_AG + lane] = (lane < 12) ? f_c : agw;
  }

  // ---- stencil: J, Fdiv, v; udiff = v @ coeffM (CFT rows, f4) ----
  float udiff;
  {
    const int* a4p = adj4 + n*4;
    const int m0 = a4p[0], m1 = a4p[1], m2 = a4p[2], m3 = a4p[3];
    const float f0 = fsrc[(b*NN+m0)*12 + c12];
    const float f1 = fsrc[(b*NN+m1)*12 + c12];
    const float f2 = fsrc[(b*NN+m2)*12 + c12];
    const float f3 = fsrc[(b*NN+m3)*12 + c12];
    const float J = 4.f * ((f0+f1+f2+f3) - 4.f*f_c);
    const float gx0 = ws[O_GPX + b*NN + m0], gx1 = ws[O_GPX + b*NN + m1];
    const float gy2 = ws[O_GPY + b*NN + m2], gy3 = ws[O_GPY + b*NN + m3];
    const float Fdiv = gx1*f1 - gx0*f0 + gy3*f3 - gy2*f2;
    const float v = ws[O_DIJ + c12]*J - ws[O_MUIJ + c12]*Fdiv;
    const float4* CFTp = (const float4*)(ws + O_CFT + c12*12);
    const float4 cf0 = CFTp[0], cf1 = CFTp[1], cf2 = CFTp[2];
    float acc;
    acc  = __shfl(v, 0) * cf0.x;
    acc  = fmaf(__shfl(v, 1), cf0.y, acc);
    acc  = fmaf(__shfl(v, 2), cf0.z, acc);
    acc  = fmaf(__shfl(v, 3), cf0.w, acc);
    acc  = fmaf(__shfl(v, 4), cf1.x, acc);
    acc  = fmaf(__shfl(v, 5), cf1.y, acc);
    acc  = fmaf(__shfl(v, 6), cf1.z, acc);
    acc  = fmaf(__shfl(v, 7), cf1.w, acc);
    acc  = fmaf(__shfl(v, 8), cf2.x, acc);
    acc  = fmaf(__shfl(v, 9), cf2.y, acc);
    acc  = fmaf(__shfl(v,10), cf2.z, acc);
    acc  = fmaf(__shfl(v,11), cf2.w, acc);
    udiff = acc;
  }

  // ---- u_rig via reverse-adjacency gather ----
  float urig;
  {
    int cnt = rcnt[wid]; if (cnt > CAP) cnt = CAP;
    const int* re = rent + wid*CAP;
    float usc = 0.f;
    if (g < 5) {
      for (int e = g; e < cnt; e += 5) {
        int pk = re[e];
        int m = pk >> 5, k = pk & 31;
        float kx = (float)(k - (k/5)*5);
        float ky = (float)(k/5);
        int base = b*NN + m;
        float fm = fsrc[base*12 + c12];
        float ax = axsrc[base*24 + c12];
        float ay = axsrc[base*24 + 12 + c12];
        float px = fmaxf(1.f - fabsf(ax - kx), 0.f);
        float py = fmaxf(1.f - fabsf(ay - ky), 0.f);
        usc = fmaf(px*py, fm, usc);
      }
    }
    usc = group5_sum(usc, lane);
    urig = usc - f_c;
  }

  // ---- h1 (trans & q, 24 dynamic rows): per-lane transposed weight rows ----
  {
    float h1t = ws[O_H1T + wid*64 + lane];
    float h1q = ws[O_H1Q + wid*64 + lane];
    const float4* WTp = (const float4*)(ws + O_WT0T + lane*24);
    const float4* WQp = (const float4*)(ws + O_WQ0T + lane*24);
    #pragma unroll
    for (int k = 0; k < 6; k++) {
      const float4 a  = *(const float4*)&shs[L_AG + 4*k];
      const float4 wt = WTp[k];
      const float4 wq = WQp[k];
      h1t = fmaf(a.x, wt.x, h1t); h1q = fmaf(a.x, wq.x, h1q);
      h1t = fmaf(a.y, wt.y, h1t); h1q = fmaf(a.y, wq.y, h1q);
      h1t = fmaf(a.z, wt.z, h1t); h1q = fmaf(a.z, wq.z, h1q);
      h1t = fmaf(a.w, wt.w, h1t); h1q = fmaf(a.w, wq.w, h1q);
    }
    shs[L_H1 + lane]      = fmaxf(h1t, 0.f);
    shs[L_H1 + 64 + lane] = fmaxf(h1q, 0.f);
  }

  // ---- h2: lanes 0-31 trans, 32-63 q ----
  const int l32 = lane & 31;
  const bool isQ = lane >= 32;
  {
    const float4* W1p = (const float4*)(ws + (isQ ? O_WQ1T : O_WT1T) + l32*64);
    const int hoff = isQ ? 64 : 0;
    float h2 = isQ ? bq1[l32] : bt1[l32];
    #pragma unroll
    for (int k = 0; k < 16; k++) {
      const float4 a = *(const float4*)&shs[L_H1 + hoff + 4*k];
      const float4 w = W1p[k];
      h2 = fmaf(a.x, w.x, h2);
      h2 = fmaf(a.y, w.y, h2);
      h2 = fmaf(a.z, w.z, h2);
      h2 = fmaf(a.w, w.w, h2);
    }
    shs[L_H2 + lane] = fmaxf(h2, 0.f);
  }

  // ---- mix logit + q0 (channel c12 per lane) ----
  float mix, q0;
  {
    const float4* WQ2p = (const float4*)(ws + O_WQ2T + c12*32);
    const float4* WZp  = (const float4*)(ws + O_WZ);
    float mixz = bt2[25];
    q0 = bq2[c12];
    #pragma unroll
    for (int k = 0; k < 8; k++) {
      const float4 at = *(const float4*)&shs[L_H2 + 4*k];
      const float4 aq = *(const float4*)&shs[L_H2 + 32 + 4*k];
      const float4 wz = WZp[k];
      const float4 wq = WQ2p[k];
      mixz = fmaf(at.x, wz.x, mixz); q0 = fmaf(aq.x, wq.x, q0);
      mixz = fmaf(at.y, wz.y, mixz); q0 = fmaf(aq.y, wq.y, q0);
      mixz = fmaf(at.z, wz.z, mixz); q0 = fmaf(aq.z, wq.z, q0);
      mixz = fmaf(at.w, wz.w, mixz); q0 = fmaf(aq.w, wq.w, q0);
    }
    mix = 1.f / (1.f + expf(-mixz));
  }

  // ---- update, outputs, next-step ax/ay ----
  const float newv = f_c + mix*udiff + (1.f - mix)*urig + q0;
  if (lane < 12) {
    shs[L_NV + lane] = newv;
    out[OQ0 + (wid*12 + lane)*TS + t] = q0;
    out[OFD + (wid*TS + t)*12 + lane] = newv;
    fdst[wid*12 + lane] = newv;
    float mass = (newv == 0.f) ? 1.f : newv;
    float mc = ws[O_MC + lane];
    float gpxn = ws[O_GPX + wid], gpyn = ws[O_GPY + wid];
    axdst[wid*24 + lane]      = fminf(fmaxf(gpxn*mc/mass, -2.f), 2.f);
    axdst[wid*24 + 12 + lane] = fminf(fmaxf(gpyn*mc/mass, -2.f), 2.f);
  }
  if (lane == 0) out[OMIX + wid*TS + t] = mix;

  // ---- dec MLP: 12(+static) -> 32 -> 32 -> 64 -> 1 ----
  {
    float d1 = ws[O_H1D + wid*32 + l32];
    const float4* WD0p = (const float4*)(ws + O_WD0T + l32*12);
    #pragma unroll
    for (int k = 0; k < 3; k++) {
      const float4 a = *(const float4*)&shs[L_NV + 4*k];
      const float4 w = WD0p[k];
      d1 = fmaf(a.x, w.x, d1);
      d1 = fmaf(a.y, w.y, d1);
      d1 = fmaf(a.z, w.z, d1);
      d1 = fmaf(a.w, w.w, d1);
    }
    if (lane < 32) shs[L_D1 + lane] = fmaxf(d1, 0.f);
  }
  {
    float d2 = bd1[l32];
    const float4* WD1p = (const float4*)(ws + O_WD1T + l32*32);
    #pragma unroll
    for (int k = 0; k < 8; k++) {
      const float4 a = *(const float4*)&shs[L_D1 + 4*k];
      const float4 w = WD1p[k];
      d2 = fmaf(a.x, w.x, d2);
      d2 = fmaf(a.y, w.y, d2);
      d2 = fmaf(a.z, w.z, d2);
      d2 = fmaf(a.w, w.w, d2);
    }
    if (lane < 32) shs[L_D2 + lane] = fmaxf(d2, 0.f);
  }
  {
    float d3 = bd2[lane];
    const float4* WD2p = (const float4*)(ws + O_WD2T + lane*32);
    #pragma unroll
    for (int k = 0; k < 8; k++) {
      const float4 a = *(const float4*)&shs[L_D2 + 4*k];
      const float4 w = WD2p[k];
      d3 = fmaf(a.x, w.x, d3);
      d3 = fmaf(a.y, w.y, d3);
      d3 = fmaf(a.z, w.z, d3);
      d3 = fmaf(a.w, w.w, d3);
    }
    float usp = fmaxf(d3, 0.f) * Wd3[lane];
    #pragma unroll
    for (int s2 = 32; s2 > 0; s2 >>= 1) usp += __shfl_xor(usp, s2);
    if (lane == 0) out[OUS + wid*TS + t] = usp + bd3[0];
  }
}

// ---------------------------------------------------------------------------
extern "C" void kernel_launch(void* const* d_in, const int* in_sizes, int n_in,
                              void* d_out, int out_size, void* d_ws, size_t ws_size,
                              hipStream_t stream) {
  const float* phi     = (const float*)d_in[0];
  const float* feat_dy = (const float*)d_in[1];
  const float* feat_st = (const float*)d_in[2];
  const float* Dv      = (const float*)d_in[3];
  const float* muv     = (const float*)d_in[4];
  const float* cv      = (const float*)d_in[5];
  const int*   adj4    = (const int*)d_in[6];
  const int*   adj25   = (const int*)d_in[7];
  const float* Wt0 = (const float*)d_in[8];
  const float* bt0 = (const float*)d_in[9];
  const float* Wt1 = (const float*)d_in[10];
  const float* bt1 = (const float*)d_in[11];
  const float* Wt2 = (const float*)d_in[12];
  const float* bt2 = (const float*)d_in[13];
  const float* Wq0 = (const float*)d_in[14];
  const float* bq0 = (const float*)d_in[15];
  const float* Wq1 = (const float*)d_in[16];
  const float* bq1 = (const float*)d_in[17];
  const float* Wq2 = (const float*)d_in[18];
  const float* bq2 = (const float*)d_in[19];
  const float* Wd0 = (const float*)d_in[20];
  const float* bd0 = (const float*)d_in[21];
  const float* Wd1 = (const float*)d_in[22];
  const float* bd1 = (const float*)d_in[23];
  const float* Wd2 = (const float*)d_in[24];
  const float* bd2 = (const float*)d_in[25];
  const float* Wd3 = (const float*)d_in[26];
  const float* bd3 = (const float*)d_in[27];

  float* ws  = (float*)d_ws;
  int*   wsi = (int*)(ws + O_FLTEND);
  float* out = (float*)d_out;

  k_setup_small<<<1, 256, 0, stream>>>(Dv, muv, cv, ws);
  k_xpose<<<16, 256, 0, stream>>>(Wt0, Wq0, Wt1, Wq1, Wt2, Wq2, Wd0, Wd1, Wd2, ws);
  k_setup_node<<<BN/4, 256, 0, stream>>>(phi, feat_dy, feat_st, adj4, adj25,
                                         Wt0, bt0, Wq0, bq0, Wd0, bd0, ws, wsi);
  k_build_rev<<<(BN*25 + 255)/256, 256, 0, stream>>>(adj25, wsi);

  float* fa = ws + O_FEATA; float* fb = ws + O_FEATB;
  float* aa = ws + O_AXYA;  float* ab = ws + O_AXYB;
  for (int t = 0; t < TS; t++) {
    k_step<<<BN/4, 256, 0, stream>>>(ws, wsi, wsi + BN, t, fa, aa, fb, ab,
                                     adj4, adj25,
                                     bt1, bq1, bt2, bq2, bd1, bd2, Wd3, bd3, out);
    float* tf = fa; fa = fb; fb = tf;
    float* ta = aa; aa = ab; ab = ta;
  }
}

// Round 5
// 1885.716 us; speedup vs baseline: 2.4577x; 1.4304x over previous
//
#include <hip/hip_runtime.h>
#include <math.h>

// ============================================================================
// ConflictNet: 30-step graph-PDE scan, B=2, N=8000, DY=12.
// Round 5: weights staged to LDS per block in b128-interleaved [quad][lane][4]
// layout (conflict-free full-BW ds_read_b128); NPW=2 nodes/wave so each weight
// read feeds 2 FMA chains; act slots in LDS with dead-region overlay.
// R4 lesson: per-lane weight rows in GLOBAL = 64-line gathers + serial chains
// -> latency-bound. LDS is the right home for a 44KB weight set.
// ============================================================================

namespace {
constexpr int NB = 2;
constexpr int NN = 8000;
constexpr int BN = NB * NN;   // 16000
constexpr int TS = 30;
constexpr int CAP = 96;

// ---- packed weight layout (shared between ws staging area and LDS) ----
constexpr int P_T0 = 0;        // [6][64][4]  Wt0 rows 0-23   (1536)
constexpr int P_Q0 = 1536;     // [6][64][4]  Wq0 rows 0-23   (1536)
constexpr int P_W1 = 3072;     // [16][64][4] Wt1|Wq1 fused   (4096)
constexpr int P_Q2 = 7168;     // [8][12][4]  Wq2             (384)
constexpr int P_Z  = 7552;     // [32]        Wt2[:,25]       (32)
constexpr int P_D0 = 7584;     // [3][32][4]  Wd0 rows 0-11   (384)
constexpr int P_D1 = 7968;     // [8][32][4]  Wd1             (1024)
constexpr int P_D2 = 8992;     // [8][64][4]  Wd2             (2048)
constexpr int P_D3 = 11040;    // [64]        Wd3             (64)
constexpr int PACK_N = 11104;  // 44.4 KB

// ---- per-node activation slot in LDS (floats); overlays:
//   AG [0,24) alive until h1;  NV [0,12) written after mix
//   H1 [24,152) alive until h2; D1 [24,56), D2 [56,88) written after
//   H2 [152,216)
constexpr int A_AG = 0;
constexpr int A_NV = 0;
constexpr int A_H1 = 24;
constexpr int A_D1 = 24;
constexpr int A_D2 = 56;
constexpr int A_H2 = 152;
constexpr int A_SLOT = 216;    // 864 B, 16B-aligned

// ---- workspace float offsets ----
constexpr int O_COEFF = 0;                 // 144
constexpr int O_CFT   = 144;               // 144 (coeffM^T, per-c12 rows)
constexpr int O_DIJ   = 288;               // 12
constexpr int O_MUIJ  = 300;               // 12
constexpr int O_MC    = 312;               // 12
constexpr int O_PACK  = 336;               // PACK_N
constexpr int O_GPX   = O_PACK + PACK_N + 16;  // BN
constexpr int O_GPY   = O_GPX + BN;
constexpr int O_H1T   = O_GPY + BN;        // BN*64
constexpr int O_H1Q   = O_H1T + BN*64;     // BN*64
constexpr int O_H1D   = O_H1Q + BN*64;     // BN*32
constexpr int O_FEATA = O_H1D + BN*32;     // BN*12
constexpr int O_FEATB = O_FEATA + BN*12;
constexpr int O_AXYA  = O_FEATB + BN*12;   // BN*24
constexpr int O_AXYB  = O_AXYA + BN*24;
constexpr int O_FLTEND= O_AXYB + BN*24;
// int region after floats: rev counts [BN], rev entries [BN*CAP]

// ---- output flat offsets ----
constexpr int OUS  = 0;
constexpr int OMIX = BN*TS;
constexpr int OQ0  = 2*BN*TS;
constexpr int OFD  = OQ0 + BN*12*TS;
}

__device__ __forceinline__ float group5_sum(float v, int lane) {
  int g = lane / 12, c = lane % 12;
  float s1 = __shfl(v, c + 12*((g+1)%5));
  float s2 = __shfl(v, c + 12*((g+2)%5));
  float s3 = __shfl(v, c + 12*((g+3)%5));
  float s4 = __shfl(v, c + 12*((g+4)%5));
  return v + s1 + s2 + s3 + s4;
}

// ---------------------------------------------------------------------------
__global__ void k_setup_small(const float* __restrict__ D, const float* __restrict__ mu,
                              const float* __restrict__ cv, float* ws) {
  int t = threadIdx.x;
  for (int e = t; e < 144; e += 256) {
    int r = e / 12, q = e % 12;
    int rb = r >> 2, cb = q >> 2, ri = r & 3, qi = q & 3;
    float val = 0.f;
    if (rb == cb) {
      int f = ri*4 + qi;
      if (f % 5 == 0) val = 1.f;
      else val = cv[64 + rb*12 + (f/5)*4 + (f%5) - 1];
    } else if (rb == 0 && cb == 2) val = cv[     ri*4 + qi];
    else if   (rb == 1 && cb == 2) val = cv[16 + ri*4 + qi];
    else if   (rb == 2 && cb == 0) val = cv[32 + ri*4 + qi];
    else if   (rb == 2 && cb == 1) val = cv[48 + ri*4 + qi];
    ws[O_COEFF + e] = fmaxf(val, 0.f);
  }
  if (t < 12) {
    ws[O_DIJ + t]  = (t < 4) ? 0.f : fmaxf(D[t-4], 0.f);
    ws[O_MUIJ + t] = (t < 4) ? fmaxf(mu[t], 0.f) : ((t < 8) ? 0.f : fmaxf(mu[t-4], 0.f));
  }
  __syncthreads();
  if (t < 144) {
    int r = t / 12, c = t % 12;
    ws[O_CFT + c*12 + r] = ws[O_COEFF + t];
  }
  if (t < 12) {
    float acc = 0.f;
    for (int c = 0; c < 12; c++) acc += ws[O_MUIJ + c] * ws[O_COEFF + c*12 + t];
    ws[O_MC + t] = acc;
  }
}

// ---------------------------------------------------------------------------
// Pack weights into b128-interleaved [quad][lane][4] layouts in ws.
// ---------------------------------------------------------------------------
__global__ void k_xpose(const float* __restrict__ Wt0, const float* __restrict__ Wq0,
                        const float* __restrict__ Wt1, const float* __restrict__ Wq1,
                        const float* __restrict__ Wt2, const float* __restrict__ Wq2,
                        const float* __restrict__ Wd0, const float* __restrict__ Wd1,
                        const float* __restrict__ Wd2, const float* __restrict__ Wd3,
                        float* ws) {
  const int t = blockIdx.x * blockDim.x + threadIdx.x;
  const int G = gridDim.x * blockDim.x;
  float* P = ws + O_PACK;
  for (int e = t; e < 1536; e += G) {           // P_T0 / P_Q0
    int q = e / 256, r = e % 256, l = r / 4, j = r % 4;
    P[P_T0 + e] = Wt0[(4*q+j)*64 + l];
    P[P_Q0 + e] = Wq0[(4*q+j)*64 + l];
  }
  for (int e = t; e < 4096; e += G) {           // P_W1 (Wt1 cols 0-31 | Wq1 cols 0-31)
    int q = e / 256, r = e % 256, l = r / 4, j = r % 4;
    P[P_W1 + e] = (l < 32) ? Wt1[(4*q+j)*32 + l] : Wq1[(4*q+j)*32 + (l-32)];
  }
  for (int e = t; e < 384; e += G) {            // P_Q2
    int q = e / 48, r = e % 48, c = r / 4, j = r % 4;
    P[P_Q2 + e] = Wq2[(4*q+j)*12 + c];
  }
  for (int e = t; e < 32; e += G) P[P_Z + e] = Wt2[e*26 + 25];
  for (int e = t; e < 384; e += G) {            // P_D0
    int q = e / 128, r = e % 128, l = r / 4, j = r % 4;
    P[P_D0 + e] = Wd0[(4*q+j)*32 + l];
  }
  for (int e = t; e < 1024; e += G) {           // P_D1
    int q = e / 128, r = e % 128, l = r / 4, j = r % 4;
    P[P_D1 + e] = Wd1[(4*q+j)*32 + l];
  }
  for (int e = t; e < 2048; e += G) {           // P_D2
    int q = e / 256, r = e % 256, l = r / 4, j = r % 4;
    P[P_D2 + e] = Wd2[(4*q+j)*64 + l];
  }
  for (int e = t; e < 64; e += G) P[P_D3 + e] = Wd3[e];
}

// ---------------------------------------------------------------------------
__global__ __launch_bounds__(256) void k_setup_node(
    const float* __restrict__ phi, const float* __restrict__ feat_dy,
    const float* __restrict__ feat_st,
    const int* __restrict__ adj4, const int* __restrict__ adj25,
    const float* __restrict__ Wt0, const float* __restrict__ bt0,
    const float* __restrict__ Wq0, const float* __restrict__ bq0,
    const float* __restrict__ Wd0, const float* __restrict__ bd0,
    float* ws, int* wsi) {
  const int wid  = (blockIdx.x * blockDim.x + threadIdx.x) >> 6;
  const int lane = threadIdx.x & 63;
  if (wid >= BN) return;
  const int b = wid / NN, n = wid % NN;

  const int* a4 = adj4 + n*4;
  const float gpx = phi[b*NN + a4[1]] - phi[b*NN + a4[0]];
  const float gpy = phi[b*NN + a4[3]] - phi[b*NN + a4[2]];
  if (lane == 0) { ws[O_GPX + wid] = gpx; ws[O_GPY + wid] = gpy; wsi[wid] = 0; }

  int idx = 0; float w = 0.f;
  if (lane < 25) { idx = adj25[n*25 + lane]; w = (lane == 0) ? 1.f : 0.01f; }
  float phiw = (lane < 25) ? w * phi[b*NN + idx] : 0.f;
  #pragma unroll
  for (int s = 32; s > 0; s >>= 1) phiw += __shfl_xor(phiw, s);

  float stv[6], stw[6];
  #pragma unroll
  for (int j = 0; j < 6; j++) {
    float x = (lane < 25) ? w * feat_st[(b*NN + idx)*6 + j] : 0.f;
    #pragma unroll
    for (int s = 32; s > 0; s >>= 1) x += __shfl_xor(x, s);
    stw[j] = x;
    stv[j] = feat_st[(b*NN + n)*6 + j];
  }
  const float phiv = phi[b*NN + n];

  float hT = bt0[lane] + phiv*Wt0[24*64 + lane] + phiw*Wt0[25*64 + lane];
  float hQ = bq0[lane] + phiv*Wq0[24*64 + lane] + phiw*Wq0[25*64 + lane];
  #pragma unroll
  for (int i = 0; i < 12; i++) {
    hT = fmaf(ws[O_DIJ  + i], Wt0[(26+i)*64 + lane], hT);
    hT = fmaf(ws[O_MUIJ + i], Wt0[(38+i)*64 + lane], hT);
  }
  #pragma unroll
  for (int j = 0; j < 6; j++) {
    hT = fmaf(stv[j], Wt0[(50+j)*64 + lane], hT);
    hT = fmaf(stw[j], Wt0[(56+j)*64 + lane], hT);
    hQ = fmaf(stv[j], Wq0[(26+j)*64 + lane], hQ);
    hQ = fmaf(stw[j], Wq0[(32+j)*64 + lane], hQ);
  }
  ws[O_H1T + wid*64 + lane] = hT;
  ws[O_H1Q + wid*64 + lane] = hQ;
  if (lane < 32) {
    float hD = bd0[lane];
    #pragma unroll
    for (int j = 0; j < 6; j++) hD = fmaf(stv[j], Wd0[(12+j)*32 + lane], hD);
    ws[O_H1D + wid*32 + lane] = hD;
  }
  if (lane < 12) {
    float f = feat_dy[wid*12 + lane];
    ws[O_FEATA + wid*12 + lane] = f;
    float mass = (f == 0.f) ? 1.f : f;
    float mc = ws[O_MC + lane];
    ws[O_AXYA + wid*24 + lane]      = fminf(fmaxf(gpx*mc/mass, -2.f), 2.f);
    ws[O_AXYA + wid*24 + 12 + lane] = fminf(fmaxf(gpy*mc/mass, -2.f), 2.f);
  }
}

// ---------------------------------------------------------------------------
__global__ void k_build_rev(const int* __restrict__ adj25, int* wsi) {
  int i = blockIdx.x * blockDim.x + threadIdx.x;
  if (i >= BN * 25) return;
  int b = i / (NN * 25);
  int rem = i % (NN * 25);
  int m = rem / 25, k = rem % 25;
  int tgt = adj25[i];
  int slot = atomicAdd(&wsi[b*NN + tgt], 1);
  if (slot < CAP) wsi[BN + (b*NN + tgt)*CAP + slot] = (m << 5) | k;
}

// ---------------------------------------------------------------------------
// Step kernel: 4 waves/block, 2 nodes/wave; weights in LDS.
// ---------------------------------------------------------------------------
__global__ __launch_bounds__(256) void k_step(
    const float* __restrict__ ws, const int* __restrict__ rcnt,
    const int* __restrict__ rent, int t,
    const float* __restrict__ fsrc, const float* __restrict__ axsrc,
    float* __restrict__ fdst, float* __restrict__ axdst,
    const int* __restrict__ adj4, const int* __restrict__ adj25,
    const float* __restrict__ bt1, const float* __restrict__ bq1,
    const float* __restrict__ bt2, const float* __restrict__ bq2,
    const float* __restrict__ bd1, const float* __restrict__ bd2,
    const float* __restrict__ bd3,
    float* __restrict__ out) {
  __shared__ __attribute__((aligned(16))) float sh[PACK_N + 8*A_SLOT];
  const int tid = threadIdx.x;
  // ---- stage packed weights into LDS (coalesced float4) ----
  {
    const float4* wp = (const float4*)(ws + O_PACK);
    float4* sp = (float4*)sh;
    for (int e = tid; e < PACK_N/4; e += 256) sp[e] = wp[e];
  }
  __syncthreads();

  const int wslot = tid >> 6;
  const int lane  = tid & 63;
  const int nb    = (blockIdx.x*4 + wslot) * 2;   // base node of the pair
  const int b  = nb / NN;
  const int n0 = nb % NN;
  const int c12 = lane % 12;
  const int g   = lane / 12;
  const int l32 = lane & 31;
  const bool isQ = lane >= 32;
  float* act0 = sh + PACK_N + (wslot*2 + 0)*A_SLOT;
  float* act1 = sh + PACK_N + (wslot*2 + 1)*A_SLOT;

  const float dij  = ws[O_DIJ  + c12];
  const float muij = ws[O_MUIJ + c12];

  float f_c[2], udiff[2], urig[2];
  #pragma unroll
  for (int j = 0; j < 2; j++) {
    const int n = n0 + j;
    const int wid = nb + j;
    float* actj = j ? act1 : act0;
    f_c[j] = fsrc[wid*12 + c12];
    // 25-neighbor aggregate
    {
      float agw = 0.f;
      if (g < 5) {
        const int* a0 = adj25 + n*25;
        #pragma unroll
        for (int kk = 0; kk < 5; kk++) {
          int k = g + 5*kk;
          float wgt = (k == 0) ? 1.f : 0.01f;
          agw = fmaf(wgt, fsrc[(b*NN + a0[k])*12 + c12], agw);
        }
      }
      agw = group5_sum(agw, lane);
      if (lane < 24) actj[A_AG + lane] = (lane < 12) ? f_c[j] : agw;
    }
    // stencil -> udiff
    {
      const int* a4p = adj4 + n*4;
      const int m0 = a4p[0], m1 = a4p[1], m2 = a4p[2], m3 = a4p[3];
      const float f0 = fsrc[(b*NN+m0)*12 + c12];
      const float f1 = fsrc[(b*NN+m1)*12 + c12];
      const float f2 = fsrc[(b*NN+m2)*12 + c12];
      const float f3 = fsrc[(b*NN+m3)*12 + c12];
      const float J = 4.f * ((f0+f1+f2+f3) - 4.f*f_c[j]);
      const float gx0 = ws[O_GPX + b*NN + m0], gx1 = ws[O_GPX + b*NN + m1];
      const float gy2 = ws[O_GPY + b*NN + m2], gy3 = ws[O_GPY + b*NN + m3];
      const float Fdiv = gx1*f1 - gx0*f0 + gy3*f3 - gy2*f2;
      const float v = dij*J - muij*Fdiv;
      const float4* CFTp = (const float4*)(ws + O_CFT + c12*12);
      const float4 cf0 = CFTp[0], cf1 = CFTp[1], cf2 = CFTp[2];
      float acc;
      acc  = __shfl(v, 0) * cf0.x;
      acc  = fmaf(__shfl(v, 1), cf0.y, acc);
      acc  = fmaf(__shfl(v, 2), cf0.z, acc);
      acc  = fmaf(__shfl(v, 3), cf0.w, acc);
      acc  = fmaf(__shfl(v, 4), cf1.x, acc);
      acc  = fmaf(__shfl(v, 5), cf1.y, acc);
      acc  = fmaf(__shfl(v, 6), cf1.z, acc);
      acc  = fmaf(__shfl(v, 7), cf1.w, acc);
      acc  = fmaf(__shfl(v, 8), cf2.x, acc);
      acc  = fmaf(__shfl(v, 9), cf2.y, acc);
      acc  = fmaf(__shfl(v,10), cf2.z, acc);
      acc  = fmaf(__shfl(v,11), cf2.w, acc);
      udiff[j] = acc;
    }
    // u_rig
    {
      int cnt = rcnt[wid]; if (cnt > CAP) cnt = CAP;
      const int* re = rent + wid*CAP;
      float usc = 0.f;
      if (g < 5) {
        for (int e = g; e < cnt; e += 5) {
          int pk = re[e];
          int m = pk >> 5, k = pk & 31;
          float kx = (float)(k - (k/5)*5);
          float ky = (float)(k/5);
          int base = b*NN + m;
          float fm = fsrc[base*12 + c12];
          float ax = axsrc[base*24 + c12];
          float ay = axsrc[base*24 + 12 + c12];
          float px = fmaxf(1.f - fabsf(ax - kx), 0.f);
          float py = fmaxf(1.f - fabsf(ay - ky), 0.f);
          usc = fmaf(px*py, fm, usc);
        }
      }
      usc = group5_sum(usc, lane);
      urig[j] = usc - f_c[j];
    }
  }

  // ---- h1: 24 dynamic rows, weights from LDS (b128, conflict-free) ----
  {
    float h1t0 = ws[O_H1T + nb*64 + lane];
    float h1q0 = ws[O_H1Q + nb*64 + lane];
    float h1t1 = ws[O_H1T + (nb+1)*64 + lane];
    float h1q1 = ws[O_H1Q + (nb+1)*64 + lane];
    #pragma unroll
    for (int q = 0; q < 6; q++) {
      const float4 wt = *(const float4*)&sh[P_T0 + q*256 + lane*4];
      const float4 wq = *(const float4*)&sh[P_Q0 + q*256 + lane*4];
      const float4 a0 = *(const float4*)&act0[A_AG + 4*q];
      const float4 a1 = *(const float4*)&act1[A_AG + 4*q];
      h1t0 = fmaf(a0.x, wt.x, h1t0); h1q0 = fmaf(a0.x, wq.x, h1q0);
      h1t0 = fmaf(a0.y, wt.y, h1t0); h1q0 = fmaf(a0.y, wq.y, h1q0);
      h1t0 = fmaf(a0.z, wt.z, h1t0); h1q0 = fmaf(a0.z, wq.z, h1q0);
      h1t0 = fmaf(a0.w, wt.w, h1t0); h1q0 = fmaf(a0.w, wq.w, h1q0);
      h1t1 = fmaf(a1.x, wt.x, h1t1); h1q1 = fmaf(a1.x, wq.x, h1q1);
      h1t1 = fmaf(a1.y, wt.y, h1t1); h1q1 = fmaf(a1.y, wq.y, h1q1);
      h1t1 = fmaf(a1.z, wt.z, h1t1); h1q1 = fmaf(a1.z, wq.z, h1q1);
      h1t1 = fmaf(a1.w, wt.w, h1t1); h1q1 = fmaf(a1.w, wq.w, h1q1);
    }
    act0[A_H1 + lane]      = fmaxf(h1t0, 0.f);
    act0[A_H1 + 64 + lane] = fmaxf(h1q0, 0.f);
    act1[A_H1 + lane]      = fmaxf(h1t1, 0.f);
    act1[A_H1 + 64 + lane] = fmaxf(h1q1, 0.f);
  }

  // ---- h2: lanes 0-31 trans, 32-63 q (fused weight block) ----
  {
    const int hoff = isQ ? 64 : 0;
    float h2_0 = isQ ? bq1[l32] : bt1[l32];
    float h2_1 = h2_0;
    #pragma unroll
    for (int q = 0; q < 16; q++) {
      const float4 w  = *(const float4*)&sh[P_W1 + q*256 + lane*4];
      const float4 a0 = *(const float4*)&act0[A_H1 + hoff + 4*q];
      const float4 a1 = *(const float4*)&act1[A_H1 + hoff + 4*q];
      h2_0 = fmaf(a0.x, w.x, h2_0); h2_1 = fmaf(a1.x, w.x, h2_1);
      h2_0 = fmaf(a0.y, w.y, h2_0); h2_1 = fmaf(a1.y, w.y, h2_1);
      h2_0 = fmaf(a0.z, w.z, h2_0); h2_1 = fmaf(a1.z, w.z, h2_1);
      h2_0 = fmaf(a0.w, w.w, h2_0); h2_1 = fmaf(a1.w, w.w, h2_1);
    }
    act0[A_H2 + lane] = fmaxf(h2_0, 0.f);
    act1[A_H2 + lane] = fmaxf(h2_1, 0.f);
  }

  // ---- mix logit + q0 ----
  float mix[2], q0v[2];
  {
    float mz0 = bt2[25], mz1 = mz0;
    float q00 = bq2[c12], q01 = q00;
    #pragma unroll
    for (int q = 0; q < 8; q++) {
      const float4 wz  = *(const float4*)&sh[P_Z + 4*q];
      const float4 wq  = *(const float4*)&sh[P_Q2 + q*48 + c12*4];
      const float4 at0 = *(const float4*)&act0[A_H2 + 4*q];
      const float4 aq0 = *(const float4*)&act0[A_H2 + 32 + 4*q];
      const float4 at1 = *(const float4*)&act1[A_H2 + 4*q];
      const float4 aq1 = *(const float4*)&act1[A_H2 + 32 + 4*q];
      mz0 = fmaf(at0.x, wz.x, mz0); q00 = fmaf(aq0.x, wq.x, q00);
      mz0 = fmaf(at0.y, wz.y, mz0); q00 = fmaf(aq0.y, wq.y, q00);
      mz0 = fmaf(at0.z, wz.z, mz0); q00 = fmaf(aq0.z, wq.z, q00);
      mz0 = fmaf(at0.w, wz.w, mz0); q00 = fmaf(aq0.w, wq.w, q00);
      mz1 = fmaf(at1.x, wz.x, mz1); q01 = fmaf(aq1.x, wq.x, q01);
      mz1 = fmaf(at1.y, wz.y, mz1); q01 = fmaf(aq1.y, wq.y, q01);
      mz1 = fmaf(at1.z, wz.z, mz1); q01 = fmaf(aq1.z, wq.z, q01);
      mz1 = fmaf(at1.w, wz.w, mz1); q01 = fmaf(aq1.w, wq.w, q01);
    }
    mix[0] = 1.f / (1.f + expf(-mz0));
    mix[1] = 1.f / (1.f + expf(-mz1));
    q0v[0] = q00; q0v[1] = q01;
  }

  // ---- update + outputs + next ax/ay ----
  #pragma unroll
  for (int j = 0; j < 2; j++) {
    const int wid = nb + j;
    float* actj = j ? act1 : act0;
    const float newv = f_c[j] + mix[j]*udiff[j] + (1.f - mix[j])*urig[j] + q0v[j];
    if (lane < 12) {
      actj[A_NV + lane] = newv;                 // overlays dead AG
      out[OQ0 + (wid*12 + lane)*TS + t] = q0v[j];
      out[OFD + (wid*TS + t)*12 + lane] = newv;
      fdst[wid*12 + lane] = newv;
      float mass = (newv == 0.f) ? 1.f : newv;
      float mc = ws[O_MC + lane];
      float gpxn = ws[O_GPX + wid], gpyn = ws[O_GPY + wid];
      axdst[wid*24 + lane]      = fminf(fmaxf(gpxn*mc/mass, -2.f), 2.f);
      axdst[wid*24 + 12 + lane] = fminf(fmaxf(gpyn*mc/mass, -2.f), 2.f);
    }
    if (lane == 0) out[OMIX + wid*TS + t] = mix[j];
  }

  // ---- dec: 12 -> 32 -> 32 -> 64 -> 1 ----
  {
    float d1_0 = ws[O_H1D + nb*32 + l32];
    float d1_1 = ws[O_H1D + (nb+1)*32 + l32];
    #pragma unroll
    for (int q = 0; q < 3; q++) {
      const float4 w  = *(const float4*)&sh[P_D0 + q*128 + l32*4];
      const float4 a0 = *(const float4*)&act0[A_NV + 4*q];
      const float4 a1 = *(const float4*)&act1[A_NV + 4*q];
      d1_0 = fmaf(a0.x, w.x, d1_0); d1_1 = fmaf(a1.x, w.x, d1_1);
      d1_0 = fmaf(a0.y, w.y, d1_0); d1_1 = fmaf(a1.y, w.y, d1_1);
      d1_0 = fmaf(a0.z, w.z, d1_0); d1_1 = fmaf(a1.z, w.z, d1_1);
      d1_0 = fmaf(a0.w, w.w, d1_0); d1_1 = fmaf(a1.w, w.w, d1_1);
    }
    if (lane < 32) {                            // overlays dead H1[0:32]
      act0[A_D1 + lane] = fmaxf(d1_0, 0.f);
      act1[A_D1 + lane] = fmaxf(d1_1, 0.f);
    }
  }
  {
    float d2_0 = bd1[l32], d2_1 = d2_0;
    #pragma unroll
    for (int q = 0; q < 8; q++) {
      const float4 w  = *(const float4*)&sh[P_D1 + q*128 + l32*4];
      const float4 a0 = *(const float4*)&act0[A_D1 + 4*q];
      const float4 a1 = *(const float4*)&act1[A_D1 + 4*q];
      d2_0 = fmaf(a0.x, w.x, d2_0); d2_1 = fmaf(a1.x, w.x, d2_1);
      d2_0 = fmaf(a0.y, w.y, d2_0); d2_1 = fmaf(a1.y, w.y, d2_1);
      d2_0 = fmaf(a0.z, w.z, d2_0); d2_1 = fmaf(a1.z, w.z, d2_1);
      d2_0 = fmaf(a0.w, w.w, d2_0); d2_1 = fmaf(a1.w, w.w, d2_1);
    }
    if (lane < 32) {                            // overlays dead H1[32:64]
      act0[A_D2 + lane] = fmaxf(d2_0, 0.f);
      act1[A_D2 + lane] = fmaxf(d2_1, 0.f);
    }
  }
  {
    float d3_0 = bd2[lane], d3_1 = d3_0;
    #pragma unroll
    for (int q = 0; q < 8; q++) {
      const float4 w  = *(const float4*)&sh[P_D2 + q*256 + lane*4];
      const float4 a0 = *(const float4*)&act0[A_D2 + 4*q];
      const float4 a1 = *(const float4*)&act1[A_D2 + 4*q];
      d3_0 = fmaf(a0.x, w.x, d3_0); d3_1 = fmaf(a1.x, w.x, d3_1);
      d3_0 = fmaf(a0.y, w.y, d3_0); d3_1 = fmaf(a1.y, w.y, d3_1);
      d3_0 = fmaf(a0.z, w.z, d3_0); d3_1 = fmaf(a1.z, w.z, d3_1);
      d3_0 = fmaf(a0.w, w.w, d3_0); d3_1 = fmaf(a1.w, w.w, d3_1);
    }
    const float wd3 = sh[P_D3 + lane];
    float u0 = fmaxf(d3_0, 0.f) * wd3;
    float u1 = fmaxf(d3_1, 0.f) * wd3;
    #pragma unroll
    for (int s2 = 32; s2 > 0; s2 >>= 1) {
      u0 += __shfl_xor(u0, s2);
      u1 += __shfl_xor(u1, s2);
    }
    if (lane == 0) {
      out[OUS + nb*TS + t]     = u0 + bd3[0];
      out[OUS + (nb+1)*TS + t] = u1 + bd3[0];
    }
  }
}

// ---------------------------------------------------------------------------
extern "C" void kernel_launch(void* const* d_in, const int* in_sizes, int n_in,
                              void* d_out, int out_size, void* d_ws, size_t ws_size,
                              hipStream_t stream) {
  const float* phi     = (const float*)d_in[0];
  const float* feat_dy = (const float*)d_in[1];
  const float* feat_st = (const float*)d_in[2];
  const float* Dv      = (const float*)d_in[3];
  const float* muv     = (const float*)d_in[4];
  const float* cv      = (const float*)d_in[5];
  const int*   adj4    = (const int*)d_in[6];
  const int*   adj25   = (const int*)d_in[7];
  const float* Wt0 = (const float*)d_in[8];
  const float* bt0 = (const float*)d_in[9];
  const float* Wt1 = (const float*)d_in[10];
  const float* bt1 = (const float*)d_in[11];
  const float* Wt2 = (const float*)d_in[12];
  const float* bt2 = (const float*)d_in[13];
  const float* Wq0 = (const float*)d_in[14];
  const float* bq0 = (const float*)d_in[15];
  const float* Wq1 = (const float*)d_in[16];
  const float* bq1 = (const float*)d_in[17];
  const float* Wq2 = (const float*)d_in[18];
  const float* bq2 = (const float*)d_in[19];
  const float* Wd0 = (const float*)d_in[20];
  const float* bd0 = (const float*)d_in[21];
  const float* Wd1 = (const float*)d_in[22];
  const float* bd1 = (const float*)d_in[23];
  const float* Wd2 = (const float*)d_in[24];
  const float* bd2 = (const float*)d_in[25];
  const float* Wd3 = (const float*)d_in[26];
  const float* bd3 = (const float*)d_in[27];

  float* ws  = (float*)d_ws;
  int*   wsi = (int*)(ws + O_FLTEND);
  float* out = (float*)d_out;

  k_setup_small<<<1, 256, 0, stream>>>(Dv, muv, cv, ws);
  k_xpose<<<16, 256, 0, stream>>>(Wt0, Wq0, Wt1, Wq1, Wt2, Wq2, Wd0, Wd1, Wd2, Wd3, ws);
  k_setup_node<<<BN/4, 256, 0, stream>>>(phi, feat_dy, feat_st, adj4, adj25,
                                         Wt0, bt0, Wq0, bq0, Wd0, bd0, ws, wsi);
  k_build_rev<<<(BN*25 + 255)/256, 256, 0, stream>>>(adj25, wsi);

  float* fa = ws + O_FEATA; float* fb = ws + O_FEATB;
  float* aa = ws + O_AXYA;  float* ab = ws + O_AXYB;
  for (int t = 0; t < TS; t++) {
    k_step<<<BN/8, 256, 0, stream>>>(ws, wsi, wsi + BN, t, fa, aa, fb, ab,
                                     adj4, adj25,
                                     bt1, bq1, bt2, bq2, bd1, bd2, bd3, out);
    float* tf = fa; fa = fb; fb = tf;
    float* ta = aa; aa = ab; ab = ta;
  }
}

// Round 6
// 1741.620 us; speedup vs baseline: 2.6611x; 1.0827x over previous
//
#include <hip/hip_runtime.h>
#include <math.h>

// ============================================================================
// ConflictNet: 30-step graph-PDE scan, B=2, N=8000, DY=12.
// Round 6: R5 compute body kept; changes:
//  (1) q0/us/mix written per-step into step-major ws staging (contiguous),
//      final k_out kernel does one coalesced reorder into the required
//      (…,T) layouts. Kills ~24MB/step of 64B-line write-allocate scatter.
//      Guarded by ws_size (falls back to R5 direct writes).
//  (2) 512-thread blocks, grid 500, 2 passes/wave: weight staging /4,
//      LDS 58.2KB -> 2 blocks/CU = 16 waves/CU (was 12).
// ============================================================================

namespace {
constexpr int NB = 2;
constexpr int NN = 8000;
constexpr int BN = NB * NN;   // 16000
constexpr int TS = 30;
constexpr int CAP = 96;

// ---- packed weight layout (ws staging area and LDS) ----
constexpr int P_T0 = 0;        // [6][64][4]  Wt0 rows 0-23   (1536)
constexpr int P_Q0 = 1536;     // [6][64][4]  Wq0 rows 0-23   (1536)
constexpr int P_W1 = 3072;     // [16][64][4] Wt1|Wq1 fused   (4096)
constexpr int P_Q2 = 7168;     // [8][12][4]  Wq2             (384)
constexpr int P_Z  = 7552;     // [32]        Wt2[:,25]       (32)
constexpr int P_D0 = 7584;     // [3][32][4]  Wd0 rows 0-11   (384)
constexpr int P_D1 = 7968;     // [8][32][4]  Wd1             (1024)
constexpr int P_D2 = 8992;     // [8][64][4]  Wd2             (2048)
constexpr int P_D3 = 11040;    // [64]        Wd3             (64)
constexpr int PACK_N = 11104;  // 44.4 KB

// ---- per-node activation slot in LDS (floats) ----
constexpr int A_AG = 0;
constexpr int A_NV = 0;
constexpr int A_H1 = 24;
constexpr int A_D1 = 24;
constexpr int A_D2 = 56;
constexpr int A_H2 = 152;
constexpr int A_SLOT = 216;    // 864 B

// ---- workspace float offsets ----
constexpr int O_COEFF = 0;                 // 144
constexpr int O_CFT   = 144;               // 144
constexpr int O_DIJ   = 288;               // 12
constexpr int O_MUIJ  = 300;               // 12
constexpr int O_MC    = 312;               // 12
constexpr int O_PACK  = 336;               // PACK_N
constexpr int O_GPX   = O_PACK + PACK_N + 16;  // BN
constexpr int O_GPY   = O_GPX + BN;
constexpr int O_H1T   = O_GPY + BN;        // BN*64
constexpr int O_H1Q   = O_H1T + BN*64;     // BN*64
constexpr int O_H1D   = O_H1Q + BN*64;     // BN*32
constexpr int O_FEATA = O_H1D + BN*32;     // BN*12
constexpr int O_FEATB = O_FEATA + BN*12;
constexpr int O_AXYA  = O_FEATB + BN*12;   // BN*24
constexpr int O_AXYB  = O_AXYA + BN*24;
constexpr int O_FLTEND= O_AXYB + BN*24;
// int region: rev counts [BN], rev entries [BN*CAP]
constexpr int O_STG   = O_FLTEND + BN + BN*CAP;   // output staging (floats)
constexpr int S_US  = 0;            // [TS][BN]
constexpr int S_MIX = TS*BN;        // [TS][BN]
constexpr int S_Q0  = 2*TS*BN;      // [TS][BN*12]
constexpr int STG_N = TS*BN*14;
constexpr size_t WS_NEED = (size_t)(O_STG + STG_N) * 4;

// ---- output flat offsets ----
constexpr int OUS  = 0;
constexpr int OMIX = BN*TS;
constexpr int OQ0  = 2*BN*TS;
constexpr int OFD  = OQ0 + BN*12*TS;
}

__device__ __forceinline__ float group5_sum(float v, int lane) {
  int g = lane / 12, c = lane % 12;
  float s1 = __shfl(v, c + 12*((g+1)%5));
  float s2 = __shfl(v, c + 12*((g+2)%5));
  float s3 = __shfl(v, c + 12*((g+3)%5));
  float s4 = __shfl(v, c + 12*((g+4)%5));
  return v + s1 + s2 + s3 + s4;
}

// ---------------------------------------------------------------------------
__global__ void k_setup_small(const float* __restrict__ D, const float* __restrict__ mu,
                              const float* __restrict__ cv, float* ws) {
  int t = threadIdx.x;
  for (int e = t; e < 144; e += 256) {
    int r = e / 12, q = e % 12;
    int rb = r >> 2, cb = q >> 2, ri = r & 3, qi = q & 3;
    float val = 0.f;
    if (rb == cb) {
      int f = ri*4 + qi;
      if (f % 5 == 0) val = 1.f;
      else val = cv[64 + rb*12 + (f/5)*4 + (f%5) - 1];
    } else if (rb == 0 && cb == 2) val = cv[     ri*4 + qi];
    else if   (rb == 1 && cb == 2) val = cv[16 + ri*4 + qi];
    else if   (rb == 2 && cb == 0) val = cv[32 + ri*4 + qi];
    else if   (rb == 2 && cb == 1) val = cv[48 + ri*4 + qi];
    ws[O_COEFF + e] = fmaxf(val, 0.f);
  }
  if (t < 12) {
    ws[O_DIJ + t]  = (t < 4) ? 0.f : fmaxf(D[t-4], 0.f);
    ws[O_MUIJ + t] = (t < 4) ? fmaxf(mu[t], 0.f) : ((t < 8) ? 0.f : fmaxf(mu[t-4], 0.f));
  }
  __syncthreads();
  if (t < 144) {
    int r = t / 12, c = t % 12;
    ws[O_CFT + c*12 + r] = ws[O_COEFF + t];
  }
  if (t < 12) {
    float acc = 0.f;
    for (int c = 0; c < 12; c++) acc += ws[O_MUIJ + c] * ws[O_COEFF + c*12 + t];
    ws[O_MC + t] = acc;
  }
}

// ---------------------------------------------------------------------------
__global__ void k_xpose(const float* __restrict__ Wt0, const float* __restrict__ Wq0,
                        const float* __restrict__ Wt1, const float* __restrict__ Wq1,
                        const float* __restrict__ Wt2, const float* __restrict__ Wq2,
                        const float* __restrict__ Wd0, const float* __restrict__ Wd1,
                        const float* __restrict__ Wd2, const float* __restrict__ Wd3,
                        float* ws) {
  const int t = blockIdx.x * blockDim.x + threadIdx.x;
  const int G = gridDim.x * blockDim.x;
  float* P = ws + O_PACK;
  for (int e = t; e < 1536; e += G) {
    int q = e / 256, r = e % 256, l = r / 4, j = r % 4;
    P[P_T0 + e] = Wt0[(4*q+j)*64 + l];
    P[P_Q0 + e] = Wq0[(4*q+j)*64 + l];
  }
  for (int e = t; e < 4096; e += G) {
    int q = e / 256, r = e % 256, l = r / 4, j = r % 4;
    P[P_W1 + e] = (l < 32) ? Wt1[(4*q+j)*32 + l] : Wq1[(4*q+j)*32 + (l-32)];
  }
  for (int e = t; e < 384; e += G) {
    int q = e / 48, r = e % 48, c = r / 4, j = r % 4;
    P[P_Q2 + e] = Wq2[(4*q+j)*12 + c];
  }
  for (int e = t; e < 32; e += G) P[P_Z + e] = Wt2[e*26 + 25];
  for (int e = t; e < 384; e += G) {
    int q = e / 128, r = e % 128, l = r / 4, j = r % 4;
    P[P_D0 + e] = Wd0[(4*q+j)*32 + l];
  }
  for (int e = t; e < 1024; e += G) {
    int q = e / 128, r = e % 128, l = r / 4, j = r % 4;
    P[P_D1 + e] = Wd1[(4*q+j)*32 + l];
  }
  for (int e = t; e < 2048; e += G) {
    int q = e / 256, r = e % 256, l = r / 4, j = r % 4;
    P[P_D2 + e] = Wd2[(4*q+j)*64 + l];
  }
  for (int e = t; e < 64; e += G) P[P_D3 + e] = Wd3[e];
}

// ---------------------------------------------------------------------------
__global__ __launch_bounds__(256) void k_setup_node(
    const float* __restrict__ phi, const float* __restrict__ feat_dy,
    const float* __restrict__ feat_st,
    const int* __restrict__ adj4, const int* __restrict__ adj25,
    const float* __restrict__ Wt0, const float* __restrict__ bt0,
    const float* __restrict__ Wq0, const float* __restrict__ bq0,
    const float* __restrict__ Wd0, const float* __restrict__ bd0,
    float* ws, int* wsi) {
  const int wid  = (blockIdx.x * blockDim.x + threadIdx.x) >> 6;
  const int lane = threadIdx.x & 63;
  if (wid >= BN) return;
  const int b = wid / NN, n = wid % NN;

  const int* a4 = adj4 + n*4;
  const float gpx = phi[b*NN + a4[1]] - phi[b*NN + a4[0]];
  const float gpy = phi[b*NN + a4[3]] - phi[b*NN + a4[2]];
  if (lane == 0) { ws[O_GPX + wid] = gpx; ws[O_GPY + wid] = gpy; wsi[wid] = 0; }

  int idx = 0; float w = 0.f;
  if (lane < 25) { idx = adj25[n*25 + lane]; w = (lane == 0) ? 1.f : 0.01f; }
  float phiw = (lane < 25) ? w * phi[b*NN + idx] : 0.f;
  #pragma unroll
  for (int s = 32; s > 0; s >>= 1) phiw += __shfl_xor(phiw, s);

  float stv[6], stw[6];
  #pragma unroll
  for (int j = 0; j < 6; j++) {
    float x = (lane < 25) ? w * feat_st[(b*NN + idx)*6 + j] : 0.f;
    #pragma unroll
    for (int s = 32; s > 0; s >>= 1) x += __shfl_xor(x, s);
    stw[j] = x;
    stv[j] = feat_st[(b*NN + n)*6 + j];
  }
  const float phiv = phi[b*NN + n];

  float hT = bt0[lane] + phiv*Wt0[24*64 + lane] + phiw*Wt0[25*64 + lane];
  float hQ = bq0[lane] + phiv*Wq0[24*64 + lane] + phiw*Wq0[25*64 + lane];
  #pragma unroll
  for (int i = 0; i < 12; i++) {
    hT = fmaf(ws[O_DIJ  + i], Wt0[(26+i)*64 + lane], hT);
    hT = fmaf(ws[O_MUIJ + i], Wt0[(38+i)*64 + lane], hT);
  }
  #pragma unroll
  for (int j = 0; j < 6; j++) {
    hT = fmaf(stv[j], Wt0[(50+j)*64 + lane], hT);
    hT = fmaf(stw[j], Wt0[(56+j)*64 + lane], hT);
    hQ = fmaf(stv[j], Wq0[(26+j)*64 + lane], hQ);
    hQ = fmaf(stw[j], Wq0[(32+j)*64 + lane], hQ);
  }
  ws[O_H1T + wid*64 + lane] = hT;
  ws[O_H1Q + wid*64 + lane] = hQ;
  if (lane < 32) {
    float hD = bd0[lane];
    #pragma unroll
    for (int j = 0; j < 6; j++) hD = fmaf(stv[j], Wd0[(12+j)*32 + lane], hD);
    ws[O_H1D + wid*32 + lane] = hD;
  }
  if (lane < 12) {
    float f = feat_dy[wid*12 + lane];
    ws[O_FEATA + wid*12 + lane] = f;
    float mass = (f == 0.f) ? 1.f : f;
    float mc = ws[O_MC + lane];
    ws[O_AXYA + wid*24 + lane]      = fminf(fmaxf(gpx*mc/mass, -2.f), 2.f);
    ws[O_AXYA + wid*24 + 12 + lane] = fminf(fmaxf(gpy*mc/mass, -2.f), 2.f);
  }
}

// ---------------------------------------------------------------------------
__global__ void k_build_rev(const int* __restrict__ adj25, int* wsi) {
  int i = blockIdx.x * blockDim.x + threadIdx.x;
  if (i >= BN * 25) return;
  int b = i / (NN * 25);
  int rem = i % (NN * 25);
  int m = rem / 25, k = rem % 25;
  int tgt = adj25[i];
  int slot = atomicAdd(&wsi[b*NN + tgt], 1);
  if (slot < CAP) wsi[BN + (b*NN + tgt)*CAP + slot] = (m << 5) | k;
}

// ---------------------------------------------------------------------------
// Step kernel: 512 threads = 8 waves; 2 passes/wave of a 2-node pair.
// Weights staged once per block.  Outputs q0/us/mix -> step-major staging.
// ---------------------------------------------------------------------------
__global__ __launch_bounds__(512) void k_step(
    const float* __restrict__ ws, const int* __restrict__ rcnt,
    const int* __restrict__ rent, int t,
    const float* __restrict__ fsrc, const float* __restrict__ axsrc,
    float* __restrict__ fdst, float* __restrict__ axdst,
    const int* __restrict__ adj4, const int* __restrict__ adj25,
    const float* __restrict__ bt1, const float* __restrict__ bq1,
    const float* __restrict__ bt2, const float* __restrict__ bq2,
    const float* __restrict__ bd1, const float* __restrict__ bd2,
    const float* __restrict__ bd3,
    float* stg, int use_stage,
    float* __restrict__ out) {
  __shared__ __attribute__((aligned(16))) float sh[PACK_N + 16*A_SLOT];
  const int tid = threadIdx.x;
  {
    const float4* wp = (const float4*)(ws + O_PACK);
    float4* sp = (float4*)sh;
    for (int e = tid; e < PACK_N/4; e += 512) sp[e] = wp[e];
  }
  __syncthreads();

  const int wv   = tid >> 6;
  const int lane = tid & 63;
  const int c12 = lane % 12;
  const int g   = lane / 12;
  const int l32 = lane & 31;
  const bool isQ = lane >= 32;
  float* act0 = sh + PACK_N + (wv*2 + 0)*A_SLOT;
  float* act1 = sh + PACK_N + (wv*2 + 1)*A_SLOT;

  const float dij  = ws[O_DIJ  + c12];
  const float muij = ws[O_MUIJ + c12];
  const float4* CFTp = (const float4*)(ws + O_CFT + c12*12);
  const float4 cf0 = CFTp[0], cf1 = CFTp[1], cf2 = CFTp[2];
  const float mcv = ws[O_MC + c12];

  #pragma unroll 1
  for (int pass = 0; pass < 2; pass++) {
    const int nb = (blockIdx.x*16 + pass*8 + wv) * 2;  // base node of pair
    const int b  = nb / NN;
    const int n0 = nb % NN;

    float f_c[2], udiff[2], urig[2];
    #pragma unroll
    for (int j = 0; j < 2; j++) {
      const int n = n0 + j;
      const int wid = nb + j;
      float* actj = j ? act1 : act0;
      f_c[j] = fsrc[wid*12 + c12];
      // 25-neighbor aggregate
      {
        float agw = 0.f;
        if (g < 5) {
          const int* a0 = adj25 + n*25;
          #pragma unroll
          for (int kk = 0; kk < 5; kk++) {
            int k = g + 5*kk;
            float wgt = (k == 0) ? 1.f : 0.01f;
            agw = fmaf(wgt, fsrc[(b*NN + a0[k])*12 + c12], agw);
          }
        }
        agw = group5_sum(agw, lane);
        if (lane < 24) actj[A_AG + lane] = (lane < 12) ? f_c[j] : agw;
      }
      // stencil -> udiff
      {
        const int* a4p = adj4 + n*4;
        const int m0 = a4p[0], m1 = a4p[1], m2 = a4p[2], m3 = a4p[3];
        const float f0 = fsrc[(b*NN+m0)*12 + c12];
        const float f1 = fsrc[(b*NN+m1)*12 + c12];
        const float f2 = fsrc[(b*NN+m2)*12 + c12];
        const float f3 = fsrc[(b*NN+m3)*12 + c12];
        const float J = 4.f * ((f0+f1+f2+f3) - 4.f*f_c[j]);
        const float gx0 = ws[O_GPX + b*NN + m0], gx1 = ws[O_GPX + b*NN + m1];
        const float gy2 = ws[O_GPY + b*NN + m2], gy3 = ws[O_GPY + b*NN + m3];
        const float Fdiv = gx1*f1 - gx0*f0 + gy3*f3 - gy2*f2;
        const float v = dij*J - muij*Fdiv;
        float acc;
        acc  = __shfl(v, 0) * cf0.x;
        acc  = fmaf(__shfl(v, 1), cf0.y, acc);
        acc  = fmaf(__shfl(v, 2), cf0.z, acc);
        acc  = fmaf(__shfl(v, 3), cf0.w, acc);
        acc  = fmaf(__shfl(v, 4), cf1.x, acc);
        acc  = fmaf(__shfl(v, 5), cf1.y, acc);
        acc  = fmaf(__shfl(v, 6), cf1.z, acc);
        acc  = fmaf(__shfl(v, 7), cf1.w, acc);
        acc  = fmaf(__shfl(v, 8), cf2.x, acc);
        acc  = fmaf(__shfl(v, 9), cf2.y, acc);
        acc  = fmaf(__shfl(v,10), cf2.z, acc);
        acc  = fmaf(__shfl(v,11), cf2.w, acc);
        udiff[j] = acc;
      }
      // u_rig
      {
        int cnt = rcnt[wid]; if (cnt > CAP) cnt = CAP;
        const int* re = rent + wid*CAP;
        float usc = 0.f;
        if (g < 5) {
          for (int e = g; e < cnt; e += 5) {
            int pk = re[e];
            int m = pk >> 5, k = pk & 31;
            float kx = (float)(k - (k/5)*5);
            float ky = (float)(k/5);
            int base = b*NN + m;
            float fm = fsrc[base*12 + c12];
            float ax = axsrc[base*24 + c12];
            float ay = axsrc[base*24 + 12 + c12];
            float px = fmaxf(1.f - fabsf(ax - kx), 0.f);
            float py = fmaxf(1.f - fabsf(ay - ky), 0.f);
            usc = fmaf(px*py, fm, usc);
          }
        }
        usc = group5_sum(usc, lane);
        urig[j] = usc - f_c[j];
      }
    }

    // ---- h1 ----
    {
      float h1t0 = ws[O_H1T + nb*64 + lane];
      float h1q0 = ws[O_H1Q + nb*64 + lane];
      float h1t1 = ws[O_H1T + (nb+1)*64 + lane];
      float h1q1 = ws[O_H1Q + (nb+1)*64 + lane];
      #pragma unroll
      for (int q = 0; q < 6; q++) {
        const float4 wt = *(const float4*)&sh[P_T0 + q*256 + lane*4];
        const float4 wq = *(const float4*)&sh[P_Q0 + q*256 + lane*4];
        const float4 a0 = *(const float4*)&act0[A_AG + 4*q];
        const float4 a1 = *(const float4*)&act1[A_AG + 4*q];
        h1t0 = fmaf(a0.x, wt.x, h1t0); h1q0 = fmaf(a0.x, wq.x, h1q0);
        h1t0 = fmaf(a0.y, wt.y, h1t0); h1q0 = fmaf(a0.y, wq.y, h1q0);
        h1t0 = fmaf(a0.z, wt.z, h1t0); h1q0 = fmaf(a0.z, wq.z, h1q0);
        h1t0 = fmaf(a0.w, wt.w, h1t0); h1q0 = fmaf(a0.w, wq.w, h1q0);
        h1t1 = fmaf(a1.x, wt.x, h1t1); h1q1 = fmaf(a1.x, wq.x, h1q1);
        h1t1 = fmaf(a1.y, wt.y, h1t1); h1q1 = fmaf(a1.y, wq.y, h1q1);
        h1t1 = fmaf(a1.z, wt.z, h1t1); h1q1 = fmaf(a1.z, wq.z, h1q1);
        h1t1 = fmaf(a1.w, wt.w, h1t1); h1q1 = fmaf(a1.w, wq.w, h1q1);
      }
      act0[A_H1 + lane]      = fmaxf(h1t0, 0.f);
      act0[A_H1 + 64 + lane] = fmaxf(h1q0, 0.f);
      act1[A_H1 + lane]      = fmaxf(h1t1, 0.f);
      act1[A_H1 + 64 + lane] = fmaxf(h1q1, 0.f);
    }

    // ---- h2 ----
    {
      const int hoff = isQ ? 64 : 0;
      float h2_0 = isQ ? bq1[l32] : bt1[l32];
      float h2_1 = h2_0;
      #pragma unroll
      for (int q = 0; q < 16; q++) {
        const float4 w  = *(const float4*)&sh[P_W1 + q*256 + lane*4];
        const float4 a0 = *(const float4*)&act0[A_H1 + hoff + 4*q];
        const float4 a1 = *(const float4*)&act1[A_H1 + hoff + 4*q];
        h2_0 = fmaf(a0.x, w.x, h2_0); h2_1 = fmaf(a1.x, w.x, h2_1);
        h2_0 = fmaf(a0.y, w.y, h2_0); h2_1 = fmaf(a1.y, w.y, h2_1);
        h2_0 = fmaf(a0.z, w.z, h2_0); h2_1 = fmaf(a1.z, w.z, h2_1);
        h2_0 = fmaf(a0.w, w.w, h2_0); h2_1 = fmaf(a1.w, w.w, h2_1);
      }
      act0[A_H2 + lane] = fmaxf(h2_0, 0.f);
      act1[A_H2 + lane] = fmaxf(h2_1, 0.f);
    }

    // ---- mix + q0 ----
    float mix[2], q0v[2];
    {
      float mz0 = bt2[25], mz1 = mz0;
      float q00 = bq2[c12], q01 = q00;
      #pragma unroll
      for (int q = 0; q < 8; q++) {
        const float4 wz  = *(const float4*)&sh[P_Z + 4*q];
        const float4 wq  = *(const float4*)&sh[P_Q2 + q*48 + c12*4];
        const float4 at0 = *(const float4*)&act0[A_H2 + 4*q];
        const float4 aq0 = *(const float4*)&act0[A_H2 + 32 + 4*q];
        const float4 at1 = *(const float4*)&act1[A_H2 + 4*q];
        const float4 aq1 = *(const float4*)&act1[A_H2 + 32 + 4*q];
        mz0 = fmaf(at0.x, wz.x, mz0); q00 = fmaf(aq0.x, wq.x, q00);
        mz0 = fmaf(at0.y, wz.y, mz0); q00 = fmaf(aq0.y, wq.y, q00);
        mz0 = fmaf(at0.z, wz.z, mz0); q00 = fmaf(aq0.z, wq.z, q00);
        mz0 = fmaf(at0.w, wz.w, mz0); q00 = fmaf(aq0.w, wq.w, q00);
        mz1 = fmaf(at1.x, wz.x, mz1); q01 = fmaf(aq1.x, wq.x, q01);
        mz1 = fmaf(at1.y, wz.y, mz1); q01 = fmaf(aq1.y, wq.y, q01);
        mz1 = fmaf(at1.z, wz.z, mz1); q01 = fmaf(aq1.z, wq.z, q01);
        mz1 = fmaf(at1.w, wz.w, mz1); q01 = fmaf(aq1.w, wq.w, q01);
      }
      mix[0] = 1.f / (1.f + expf(-mz0));
      mix[1] = 1.f / (1.f + expf(-mz1));
      q0v[0] = q00; q0v[1] = q01;
    }

    // ---- update + outputs + next ax/ay ----
    #pragma unroll
    for (int j = 0; j < 2; j++) {
      const int wid = nb + j;
      float* actj = j ? act1 : act0;
      const float newv = f_c[j] + mix[j]*udiff[j] + (1.f - mix[j])*urig[j] + q0v[j];
      if (lane < 12) {
        actj[A_NV + lane] = newv;
        if (use_stage) stg[S_Q0 + (size_t)t*BN*12 + wid*12 + lane] = q0v[j];
        else           out[OQ0 + (wid*12 + lane)*TS + t] = q0v[j];
        out[OFD + (wid*TS + t)*12 + lane] = newv;
        fdst[wid*12 + lane] = newv;
        float mass = (newv == 0.f) ? 1.f : newv;
        float gpxn = ws[O_GPX + wid], gpyn = ws[O_GPY + wid];
        axdst[wid*24 + lane]      = fminf(fmaxf(gpxn*mcv/mass, -2.f), 2.f);
        axdst[wid*24 + 12 + lane] = fminf(fmaxf(gpyn*mcv/mass, -2.f), 2.f);
      }
      if (lane == 0) {
        if (use_stage) stg[S_MIX + (size_t)t*BN + wid] = mix[j];
        else           out[OMIX + wid*TS + t] = mix[j];
      }
    }

    // ---- dec ----
    {
      float d1_0 = ws[O_H1D + nb*32 + l32];
      float d1_1 = ws[O_H1D + (nb+1)*32 + l32];
      #pragma unroll
      for (int q = 0; q < 3; q++) {
        const float4 w  = *(const float4*)&sh[P_D0 + q*128 + l32*4];
        const float4 a0 = *(const float4*)&act0[A_NV + 4*q];
        const float4 a1 = *(const float4*)&act1[A_NV + 4*q];
        d1_0 = fmaf(a0.x, w.x, d1_0); d1_1 = fmaf(a1.x, w.x, d1_1);
        d1_0 = fmaf(a0.y, w.y, d1_0); d1_1 = fmaf(a1.y, w.y, d1_1);
        d1_0 = fmaf(a0.z, w.z, d1_0); d1_1 = fmaf(a1.z, w.z, d1_1);
        d1_0 = fmaf(a0.w, w.w, d1_0); d1_1 = fmaf(a1.w, w.w, d1_1);
      }
      if (lane < 32) {
        act0[A_D1 + lane] = fmaxf(d1_0, 0.f);
        act1[A_D1 + lane] = fmaxf(d1_1, 0.f);
      }
    }
    {
      float d2_0 = bd1[l32], d2_1 = d2_0;
      #pragma unroll
      for (int q = 0; q < 8; q++) {
        const float4 w  = *(const float4*)&sh[P_D1 + q*128 + l32*4];
        const float4 a0 = *(const float4*)&act0[A_D1 + 4*q];
        const float4 a1 = *(const float4*)&act1[A_D1 + 4*q];
        d2_0 = fmaf(a0.x, w.x, d2_0); d2_1 = fmaf(a1.x, w.x, d2_1);
        d2_0 = fmaf(a0.y, w.y, d2_0); d2_1 = fmaf(a1.y, w.y, d2_1);
        d2_0 = fmaf(a0.z, w.z, d2_0); d2_1 = fmaf(a1.z, w.z, d2_1);
        d2_0 = fmaf(a0.w, w.w, d2_0); d2_1 = fmaf(a1.w, w.w, d2_1);
      }
      if (lane < 32) {
        act0[A_D2 + lane] = fmaxf(d2_0, 0.f);
        act1[A_D2 + lane] = fmaxf(d2_1, 0.f);
      }
    }
    {
      float d3_0 = bd2[lane], d3_1 = d3_0;
      #pragma unroll
      for (int q = 0; q < 8; q++) {
        const float4 w  = *(const float4*)&sh[P_D2 + q*256 + lane*4];
        const float4 a0 = *(const float4*)&act0[A_D2 + 4*q];
        const float4 a1 = *(const float4*)&act1[A_D2 + 4*q];
        d3_0 = fmaf(a0.x, w.x, d3_0); d3_1 = fmaf(a1.x, w.x, d3_1);
        d3_0 = fmaf(a0.y, w.y, d3_0); d3_1 = fmaf(a1.y, w.y, d3_1);
        d3_0 = fmaf(a0.z, w.z, d3_0); d3_1 = fmaf(a1.z, w.z, d3_1);
        d3_0 = fmaf(a0.w, w.w, d3_0); d3_1 = fmaf(a1.w, w.w, d3_1);
      }
      const float wd3 = sh[P_D3 + lane];
      float u0 = fmaxf(d3_0, 0.f) * wd3;
      float u1 = fmaxf(d3_1, 0.f) * wd3;
      #pragma unroll
      for (int s2 = 32; s2 > 0; s2 >>= 1) {
        u0 += __shfl_xor(u0, s2);
        u1 += __shfl_xor(u1, s2);
      }
      if (lane == 0) {
        if (use_stage) {
          stg[S_US + (size_t)t*BN + nb]     = u0 + bd3[0];
          stg[S_US + (size_t)t*BN + nb + 1] = u1 + bd3[0];
        } else {
          out[OUS + nb*TS + t]     = u0 + bd3[0];
          out[OUS + (nb+1)*TS + t] = u1 + bd3[0];
        }
      }
    }
  }
}

// ---------------------------------------------------------------------------
// Final reorder: staged step-major -> required (...,T) layouts. Coalesced
// writes; gather reads hit L3 (staged data ~27MB, written this launch).
// ---------------------------------------------------------------------------
__global__ void k_out(const float* __restrict__ stg, float* __restrict__ out) {
  const size_t NQ = (size_t)BN*12*TS;
  const size_t NU = (size_t)BN*TS;
  size_t i = (size_t)blockIdx.x * blockDim.x + threadIdx.x;
  if (i < NQ) {
    int e = (int)(i / TS), t = (int)(i % TS);
    out[OQ0 + i] = stg[S_Q0 + (size_t)t*BN*12 + e];
  } else if (i < NQ + NU) {
    size_t j = i - NQ;
    int n = (int)(j / TS), t = (int)(j % TS);
    out[OUS + j] = stg[S_US + (size_t)t*BN + n];
  } else if (i < NQ + 2*NU) {
    size_t j = i - NQ - NU;
    int n = (int)(j / TS), t = (int)(j % TS);
    out[OMIX + j] = stg[S_MIX + (size_t)t*BN + n];
  }
}

// ---------------------------------------------------------------------------
extern "C" void kernel_launch(void* const* d_in, const int* in_sizes, int n_in,
                              void* d_out, int out_size, void* d_ws, size_t ws_size,
                              hipStream_t stream) {
  const float* phi     = (const float*)d_in[0];
  const float* feat_dy = (const float*)d_in[1];
  const float* feat_st = (const float*)d_in[2];
  const float* Dv      = (const float*)d_in[3];
  const float* muv     = (const float*)d_in[4];
  const float* cv      = (const float*)d_in[5];
  const int*   adj4    = (const int*)d_in[6];
  const int*   adj25   = (const int*)d_in[7];
  const float* Wt0 = (const float*)d_in[8];
  const float* bt0 = (const float*)d_in[9];
  const float* Wt1 = (const float*)d_in[10];
  const float* bt1 = (const float*)d_in[11];
  const float* Wt2 = (const float*)d_in[12];
  const float* bt2 = (const float*)d_in[13];
  const float* Wq0 = (const float*)d_in[14];
  const float* bq0 = (const float*)d_in[15];
  const float* Wq1 = (const float*)d_in[16];
  const float* bq1 = (const float*)d_in[17];
  const float* Wq2 = (const float*)d_in[18];
  const float* bq2 = (const float*)d_in[19];
  const float* Wd0 = (const float*)d_in[20];
  const float* bd0 = (const float*)d_in[21];
  const float* Wd1 = (const float*)d_in[22];
  const float* bd1 = (const float*)d_in[23];
  const float* Wd2 = (const float*)d_in[24];
  const float* bd2 = (const float*)d_in[25];
  const float* Wd3 = (const float*)d_in[26];
  const float* bd3 = (const float*)d_in[27];

  float* ws  = (float*)d_ws;
  int*   wsi = (int*)(ws + O_FLTEND);
  float* out = (float*)d_out;
  const int use_stage = (ws_size >= WS_NEED) ? 1 : 0;
  float* stg = ws + O_STG;

  k_setup_small<<<1, 256, 0, stream>>>(Dv, muv, cv, ws);
  k_xpose<<<16, 256, 0, stream>>>(Wt0, Wq0, Wt1, Wq1, Wt2, Wq2, Wd0, Wd1, Wd2, Wd3, ws);
  k_setup_node<<<BN/4, 256, 0, stream>>>(phi, feat_dy, feat_st, adj4, adj25,
                                         Wt0, bt0, Wq0, bq0, Wd0, bd0, ws, wsi);
  k_build_rev<<<(BN*25 + 255)/256, 256, 0, stream>>>(adj25, wsi);

  float* fa = ws + O_FEATA; float* fb = ws + O_FEATB;
  float* aa = ws + O_AXYA;  float* ab = ws + O_AXYB;
  for (int t = 0; t < TS; t++) {
    k_step<<<BN/32, 512, 0, stream>>>(ws, wsi, wsi + BN, t, fa, aa, fb, ab,
                                      adj4, adj25,
                                      bt1, bq1, bt2, bq2, bd1, bd2, bd3,
                                      stg, use_stage, out);
    float* tf = fa; fa = fb; fb = tf;
    float* ta = aa; aa = ab; ab = ta;
  }
  if (use_stage) {
    const size_t tot = (size_t)BN*TS*14;
    k_out<<<(unsigned)((tot + 255)/256), 256, 0, stream>>>(stg, out);
  }
}

// Round 7
// 1602.942 us; speedup vs baseline: 2.8913x; 1.0865x over previous
//
#include <hip/hip_runtime.h>
#include <math.h>

// ============================================================================
// ConflictNet: 30-step graph-PDE scan, B=2, N=8000, DY=12.
// Round 7: attack vector-memory latency (R5/R6 both stuck at 63us, all pipes
// <30%):
//  (1) u_rig state packed float4 {f,ax,ay,0}: 1 dwordx4/entry vs 3 loads.
//  (2) readfirstlane(wave-id) -> adj4/adj25/rcnt/rent/gpx/gpy become SCALAR
//      loads (they are wave-uniform; compiler can't prove tid>>6 uniform).
//  (3) biases moved into the LDS weight pack.
//  (4) CAP 96->64, stage only q0 (ws budget).
// ============================================================================

namespace {
constexpr int NB = 2;
constexpr int NN = 8000;
constexpr int BN = NB * NN;   // 16000
constexpr int TS = 30;
constexpr int CAP = 64;

// ---- packed weight layout (ws staging area and LDS) ----
constexpr int P_T0 = 0;        // [6][64][4]  Wt0 rows 0-23   (1536)
constexpr int P_Q0 = 1536;     // [6][64][4]  Wq0 rows 0-23   (1536)
constexpr int P_W1 = 3072;     // [16][64][4] Wt1|Wq1 fused   (4096)
constexpr int P_Q2 = 7168;     // [8][12][4]  Wq2             (384)
constexpr int P_Z  = 7552;     // [32]        Wt2[:,25]       (32)
constexpr int P_D0 = 7584;     // [3][32][4]  Wd0 rows 0-11   (384)
constexpr int P_D1 = 7968;     // [8][32][4]  Wd1             (1024)
constexpr int P_D2 = 8992;     // [8][64][4]  Wd2             (2048)
constexpr int P_D3 = 11040;    // [64]        Wd3             (64)
constexpr int P_BT1 = 11104;   // [32] bt1
constexpr int P_BQ1 = 11136;   // [32] bq1
constexpr int P_BQ2 = 11168;   // [16] bq2 (12 used)
constexpr int P_BD1 = 11184;   // [32] bd1
constexpr int P_BD2 = 11216;   // [64] bd2
constexpr int P_MISC= 11280;   // [0]=bd3[0], [1]=bt2[25]
constexpr int PACK_N = 11296;  // 45.2 KB

// ---- per-node activation slot in LDS (floats) ----
constexpr int A_AG = 0;
constexpr int A_NV = 0;
constexpr int A_H1 = 24;
constexpr int A_D1 = 24;
constexpr int A_D2 = 56;
constexpr int A_H2 = 152;
constexpr int A_SLOT = 216;    // 864 B

// ---- workspace float offsets ----
constexpr int O_COEFF = 0;                 // 144
constexpr int O_CFT   = 144;               // 144
constexpr int O_DIJ   = 288;               // 12
constexpr int O_MUIJ  = 300;               // 12
constexpr int O_MC    = 312;               // 12
constexpr int O_PACK  = 336;               // PACK_N
constexpr int O_GPX   = O_PACK + PACK_N + 16;  // BN
constexpr int O_GPY   = O_GPX + BN;
constexpr int O_H1T   = O_GPY + BN;        // BN*64
constexpr int O_H1Q   = O_H1T + BN*64;     // BN*64
constexpr int O_H1D   = O_H1Q + BN*64;     // BN*32
constexpr int O_FEATA = O_H1D + BN*32;     // BN*12
constexpr int O_FEATB = O_FEATA + BN*12;
constexpr int O_AXY4A = O_FEATB + BN*12;   // BN*12 float4 = BN*48 floats
constexpr int O_AXY4B = O_AXY4A + BN*48;
constexpr int O_FLTEND= O_AXY4B + BN*48;
// int region: rev counts [BN], rev entries [BN*CAP]
constexpr int O_STG   = O_FLTEND + BN + BN*CAP;   // q0 staging [TS][BN*12]
constexpr int STG_N = TS*BN*12;
constexpr size_t WS_NEED = (size_t)(O_STG + STG_N) * 4;

// ---- output flat offsets ----
constexpr int OUS  = 0;
constexpr int OMIX = BN*TS;
constexpr int OQ0  = 2*BN*TS;
constexpr int OFD  = OQ0 + BN*12*TS;
}

__device__ __forceinline__ float group5_sum(float v, int lane) {
  int g = lane / 12, c = lane % 12;
  float s1 = __shfl(v, c + 12*((g+1)%5));
  float s2 = __shfl(v, c + 12*((g+2)%5));
  float s3 = __shfl(v, c + 12*((g+3)%5));
  float s4 = __shfl(v, c + 12*((g+4)%5));
  return v + s1 + s2 + s3 + s4;
}

// ---------------------------------------------------------------------------
__global__ void k_setup_small(const float* __restrict__ D, const float* __restrict__ mu,
                              const float* __restrict__ cv, float* ws) {
  int t = threadIdx.x;
  for (int e = t; e < 144; e += 256) {
    int r = e / 12, q = e % 12;
    int rb = r >> 2, cb = q >> 2, ri = r & 3, qi = q & 3;
    float val = 0.f;
    if (rb == cb) {
      int f = ri*4 + qi;
      if (f % 5 == 0) val = 1.f;
      else val = cv[64 + rb*12 + (f/5)*4 + (f%5) - 1];
    } else if (rb == 0 && cb == 2) val = cv[     ri*4 + qi];
    else if   (rb == 1 && cb == 2) val = cv[16 + ri*4 + qi];
    else if   (rb == 2 && cb == 0) val = cv[32 + ri*4 + qi];
    else if   (rb == 2 && cb == 1) val = cv[48 + ri*4 + qi];
    ws[O_COEFF + e] = fmaxf(val, 0.f);
  }
  if (t < 12) {
    ws[O_DIJ + t]  = (t < 4) ? 0.f : fmaxf(D[t-4], 0.f);
    ws[O_MUIJ + t] = (t < 4) ? fmaxf(mu[t], 0.f) : ((t < 8) ? 0.f : fmaxf(mu[t-4], 0.f));
  }
  __syncthreads();
  if (t < 144) {
    int r = t / 12, c = t % 12;
    ws[O_CFT + c*12 + r] = ws[O_COEFF + t];
  }
  if (t < 12) {
    float acc = 0.f;
    for (int c = 0; c < 12; c++) acc += ws[O_MUIJ + c] * ws[O_COEFF + c*12 + t];
    ws[O_MC + t] = acc;
  }
}

// ---------------------------------------------------------------------------
__global__ void k_xpose(const float* __restrict__ Wt0, const float* __restrict__ Wq0,
                        const float* __restrict__ Wt1, const float* __restrict__ Wq1,
                        const float* __restrict__ Wt2, const float* __restrict__ Wq2,
                        const float* __restrict__ Wd0, const float* __restrict__ Wd1,
                        const float* __restrict__ Wd2, const float* __restrict__ Wd3,
                        const float* __restrict__ bt1, const float* __restrict__ bq1,
                        const float* __restrict__ bt2, const float* __restrict__ bq2,
                        const float* __restrict__ bd1, const float* __restrict__ bd2,
                        const float* __restrict__ bd3,
                        float* ws) {
  const int t = blockIdx.x * blockDim.x + threadIdx.x;
  const int G = gridDim.x * blockDim.x;
  float* P = ws + O_PACK;
  for (int e = t; e < 1536; e += G) {
    int q = e / 256, r = e % 256, l = r / 4, j = r % 4;
    P[P_T0 + e] = Wt0[(4*q+j)*64 + l];
    P[P_Q0 + e] = Wq0[(4*q+j)*64 + l];
  }
  for (int e = t; e < 4096; e += G) {
    int q = e / 256, r = e % 256, l = r / 4, j = r % 4;
    P[P_W1 + e] = (l < 32) ? Wt1[(4*q+j)*32 + l] : Wq1[(4*q+j)*32 + (l-32)];
  }
  for (int e = t; e < 384; e += G) {
    int q = e / 48, r = e % 48, c = r / 4, j = r % 4;
    P[P_Q2 + e] = Wq2[(4*q+j)*12 + c];
  }
  for (int e = t; e < 32; e += G) P[P_Z + e] = Wt2[e*26 + 25];
  for (int e = t; e < 384; e += G) {
    int q = e / 128, r = e % 128, l = r / 4, j = r % 4;
    P[P_D0 + e] = Wd0[(4*q+j)*32 + l];
  }
  for (int e = t; e < 1024; e += G) {
    int q = e / 128, r = e % 128, l = r / 4, j = r % 4;
    P[P_D1 + e] = Wd1[(4*q+j)*32 + l];
  }
  for (int e = t; e < 2048; e += G) {
    int q = e / 256, r = e % 256, l = r / 4, j = r % 4;
    P[P_D2 + e] = Wd2[(4*q+j)*64 + l];
  }
  for (int e = t; e < 64; e += G) P[P_D3 + e] = Wd3[e];
  for (int e = t; e < 32; e += G) {
    P[P_BT1 + e] = bt1[e];
    P[P_BQ1 + e] = bq1[e];
    P[P_BD1 + e] = bd1[e];
  }
  for (int e = t; e < 12; e += G) P[P_BQ2 + e] = bq2[e];
  for (int e = t; e < 64; e += G) P[P_BD2 + e] = bd2[e];
  if (t == 0) { P[P_MISC + 0] = bd3[0]; P[P_MISC + 1] = bt2[25]; }
}

// ---------------------------------------------------------------------------
__global__ __launch_bounds__(256) void k_setup_node(
    const float* __restrict__ phi, const float* __restrict__ feat_dy,
    const float* __restrict__ feat_st,
    const int* __restrict__ adj4, const int* __restrict__ adj25,
    const float* __restrict__ Wt0, const float* __restrict__ bt0,
    const float* __restrict__ Wq0, const float* __restrict__ bq0,
    const float* __restrict__ Wd0, const float* __restrict__ bd0,
    float* ws, int* wsi) {
  const int wid  = (blockIdx.x * blockDim.x + threadIdx.x) >> 6;
  const int lane = threadIdx.x & 63;
  if (wid >= BN) return;
  const int b = wid / NN, n = wid % NN;

  const int* a4 = adj4 + n*4;
  const float gpx = phi[b*NN + a4[1]] - phi[b*NN + a4[0]];
  const float gpy = phi[b*NN + a4[3]] - phi[b*NN + a4[2]];
  if (lane == 0) { ws[O_GPX + wid] = gpx; ws[O_GPY + wid] = gpy; wsi[wid] = 0; }

  int idx = 0; float w = 0.f;
  if (lane < 25) { idx = adj25[n*25 + lane]; w = (lane == 0) ? 1.f : 0.01f; }
  float phiw = (lane < 25) ? w * phi[b*NN + idx] : 0.f;
  #pragma unroll
  for (int s = 32; s > 0; s >>= 1) phiw += __shfl_xor(phiw, s);

  float stv[6], stw[6];
  #pragma unroll
  for (int j = 0; j < 6; j++) {
    float x = (lane < 25) ? w * feat_st[(b*NN + idx)*6 + j] : 0.f;
    #pragma unroll
    for (int s = 32; s > 0; s >>= 1) x += __shfl_xor(x, s);
    stw[j] = x;
    stv[j] = feat_st[(b*NN + n)*6 + j];
  }
  const float phiv = phi[b*NN + n];

  float hT = bt0[lane] + phiv*Wt0[24*64 + lane] + phiw*Wt0[25*64 + lane];
  float hQ = bq0[lane] + phiv*Wq0[24*64 + lane] + phiw*Wq0[25*64 + lane];
  #pragma unroll
  for (int i = 0; i < 12; i++) {
    hT = fmaf(ws[O_DIJ  + i], Wt0[(26+i)*64 + lane], hT);
    hT = fmaf(ws[O_MUIJ + i], Wt0[(38+i)*64 + lane], hT);
  }
  #pragma unroll
  for (int j = 0; j < 6; j++) {
    hT = fmaf(stv[j], Wt0[(50+j)*64 + lane], hT);
    hT = fmaf(stw[j], Wt0[(56+j)*64 + lane], hT);
    hQ = fmaf(stv[j], Wq0[(26+j)*64 + lane], hQ);
    hQ = fmaf(stw[j], Wq0[(32+j)*64 + lane], hQ);
  }
  ws[O_H1T + wid*64 + lane] = hT;
  ws[O_H1Q + wid*64 + lane] = hQ;
  if (lane < 32) {
    float hD = bd0[lane];
    #pragma unroll
    for (int j = 0; j < 6; j++) hD = fmaf(stv[j], Wd0[(12+j)*32 + lane], hD);
    ws[O_H1D + wid*32 + lane] = hD;
  }
  if (lane < 12) {
    float f = feat_dy[wid*12 + lane];
    ws[O_FEATA + wid*12 + lane] = f;
    float mass = (f == 0.f) ? 1.f : f;
    float mc = ws[O_MC + lane];
    float axv = fminf(fmaxf(gpx*mc/mass, -2.f), 2.f);
    float ayv = fminf(fmaxf(gpy*mc/mass, -2.f), 2.f);
    float4* a4a = (float4*)(ws + O_AXY4A);
    a4a[wid*12 + lane] = make_float4(f, axv, ayv, 0.f);
  }
}

// ---------------------------------------------------------------------------
__global__ void k_build_rev(const int* __restrict__ adj25, int* wsi) {
  int i = blockIdx.x * blockDim.x + threadIdx.x;
  if (i >= BN * 25) return;
  int b = i / (NN * 25);
  int rem = i % (NN * 25);
  int m = rem / 25, k = rem % 25;
  int tgt = adj25[i];
  int slot = atomicAdd(&wsi[b*NN + tgt], 1);
  if (slot < CAP) wsi[BN + (b*NN + tgt)*CAP + slot] = (m << 5) | k;
}

// ---------------------------------------------------------------------------
// Step kernel: 512 threads = 8 waves; 2 passes/wave of a 2-node pair.
// ---------------------------------------------------------------------------
__global__ __launch_bounds__(512) void k_step(
    const float* __restrict__ ws, const int* __restrict__ rcnt,
    const int* __restrict__ rent, int t,
    const float* __restrict__ fsrc, const float4* __restrict__ a4src,
    float* __restrict__ fdst, float4* __restrict__ a4dst,
    const int* __restrict__ adj4, const int* __restrict__ adj25,
    float* __restrict__ stg, int use_stage,
    float* __restrict__ out) {
  __shared__ __attribute__((aligned(16))) float sh[PACK_N + 16*A_SLOT];
  const int tid = threadIdx.x;
  {
    const float4* wp = (const float4*)(ws + O_PACK);
    float4* sp = (float4*)sh;
    for (int e = tid; e < PACK_N/4; e += 512) sp[e] = wp[e];
  }
  __syncthreads();

  const int wv   = tid >> 6;
  const int wvq  = __builtin_amdgcn_readfirstlane(wv);  // uniform wave id
  const int lane = tid & 63;
  const int c12 = lane % 12;
  const int g   = lane / 12;
  const int l32 = lane & 31;
  const bool isQ = lane >= 32;
  float* act0 = sh + PACK_N + (wvq*2 + 0)*A_SLOT;
  float* act1 = sh + PACK_N + (wvq*2 + 1)*A_SLOT;

  const float dij  = ws[O_DIJ  + c12];
  const float muij = ws[O_MUIJ + c12];
  const float4* CFTp = (const float4*)(ws + O_CFT + c12*12);
  const float4 cf0 = CFTp[0], cf1 = CFTp[1], cf2 = CFTp[2];
  const float mcv = ws[O_MC + c12];

  #pragma unroll 1
  for (int pass = 0; pass < 2; pass++) {
    const int nb = (blockIdx.x*16 + pass*8 + wvq) * 2;  // uniform
    const int b  = nb / NN;
    const int n0 = nb % NN;

    float f_c[2], udiff[2], urig[2];
    #pragma unroll
    for (int j = 0; j < 2; j++) {
      const int n = n0 + j;
      const int wid = nb + j;
      float* actj = j ? act1 : act0;
      f_c[j] = fsrc[wid*12 + c12];
      // 25-neighbor aggregate
      {
        float agw = 0.f;
        if (g < 5) {
          const int* a0 = adj25 + n*25;     // uniform base -> scalar loads
          #pragma unroll
          for (int kk = 0; kk < 5; kk++) {
            int k = g + 5*kk;
            float wgt = (k == 0) ? 1.f : 0.01f;
            agw = fmaf(wgt, fsrc[(b*NN + a0[k])*12 + c12], agw);
          }
        }
        agw = group5_sum(agw, lane);
        if (lane < 24) actj[A_AG + lane] = (lane < 12) ? f_c[j] : agw;
      }
      // stencil -> udiff
      {
        const int* a4p = adj4 + n*4;        // uniform -> scalar loads
        const int m0 = a4p[0], m1 = a4p[1], m2 = a4p[2], m3 = a4p[3];
        const float f0 = fsrc[(b*NN+m0)*12 + c12];
        const float f1 = fsrc[(b*NN+m1)*12 + c12];
        const float f2 = fsrc[(b*NN+m2)*12 + c12];
        const float f3 = fsrc[(b*NN+m3)*12 + c12];
        const float J = 4.f * ((f0+f1+f2+f3) - 4.f*f_c[j]);
        const float gx0 = ws[O_GPX + b*NN + m0], gx1 = ws[O_GPX + b*NN + m1];
        const float gy2 = ws[O_GPY + b*NN + m2], gy3 = ws[O_GPY + b*NN + m3];
        const float Fdiv = gx1*f1 - gx0*f0 + gy3*f3 - gy2*f2;
        const float v = dij*J - muij*Fdiv;
        float acc;
        acc  = __shfl(v, 0) * cf0.x;
        acc  = fmaf(__shfl(v, 1), cf0.y, acc);
        acc  = fmaf(__shfl(v, 2), cf0.z, acc);
        acc  = fmaf(__shfl(v, 3), cf0.w, acc);
        acc  = fmaf(__shfl(v, 4), cf1.x, acc);
        acc  = fmaf(__shfl(v, 5), cf1.y, acc);
        acc  = fmaf(__shfl(v, 6), cf1.z, acc);
        acc  = fmaf(__shfl(v, 7), cf1.w, acc);
        acc  = fmaf(__shfl(v, 8), cf2.x, acc);
        acc  = fmaf(__shfl(v, 9), cf2.y, acc);
        acc  = fmaf(__shfl(v,10), cf2.z, acc);
        acc  = fmaf(__shfl(v,11), cf2.w, acc);
        udiff[j] = acc;
      }
      // u_rig: packed {f,ax,ay} -> ONE dwordx4 per entry
      {
        int cnt = rcnt[wid]; if (cnt > CAP) cnt = CAP;   // uniform -> scalar
        const int* re = rent + wid*CAP;
        float usc = 0.f;
        if (g < 5) {
          #pragma unroll 2
          for (int e = g; e < cnt; e += 5) {
            int pk = re[e];
            int m = pk >> 5, k = pk & 31;
            float kx = (float)(k - (k/5)*5);
            float ky = (float)(k/5);
            const float4 sm = a4src[(b*NN + m)*12 + c12];
            float px = fmaxf(1.f - fabsf(sm.y - kx), 0.f);
            float py = fmaxf(1.f - fabsf(sm.z - ky), 0.f);
            usc = fmaf(px*py, sm.x, usc);
          }
        }
        usc = group5_sum(usc, lane);
        urig[j] = usc - f_c[j];
      }
    }

    // ---- h1 ----
    {
      float h1t0 = ws[O_H1T + nb*64 + lane];
      float h1q0 = ws[O_H1Q + nb*64 + lane];
      float h1t1 = ws[O_H1T + (nb+1)*64 + lane];
      float h1q1 = ws[O_H1Q + (nb+1)*64 + lane];
      #pragma unroll
      for (int q = 0; q < 6; q++) {
        const float4 wt = *(const float4*)&sh[P_T0 + q*256 + lane*4];
        const float4 wq = *(const float4*)&sh[P_Q0 + q*256 + lane*4];
        const float4 a0 = *(const float4*)&act0[A_AG + 4*q];
        const float4 a1 = *(const float4*)&act1[A_AG + 4*q];
        h1t0 = fmaf(a0.x, wt.x, h1t0); h1q0 = fmaf(a0.x, wq.x, h1q0);
        h1t0 = fmaf(a0.y, wt.y, h1t0); h1q0 = fmaf(a0.y, wq.y, h1q0);
        h1t0 = fmaf(a0.z, wt.z, h1t0); h1q0 = fmaf(a0.z, wq.z, h1q0);
        h1t0 = fmaf(a0.w, wt.w, h1t0); h1q0 = fmaf(a0.w, wq.w, h1q0);
        h1t1 = fmaf(a1.x, wt.x, h1t1); h1q1 = fmaf(a1.x, wq.x, h1q1);
        h1t1 = fmaf(a1.y, wt.y, h1t1); h1q1 = fmaf(a1.y, wq.y, h1q1);
        h1t1 = fmaf(a1.z, wt.z, h1t1); h1q1 = fmaf(a1.z, wq.z, h1q1);
        h1t1 = fmaf(a1.w, wt.w, h1t1); h1q1 = fmaf(a1.w, wq.w, h1q1);
      }
      act0[A_H1 + lane]      = fmaxf(h1t0, 0.f);
      act0[A_H1 + 64 + lane] = fmaxf(h1q0, 0.f);
      act1[A_H1 + lane]      = fmaxf(h1t1, 0.f);
      act1[A_H1 + 64 + lane] = fmaxf(h1q1, 0.f);
    }

    // ---- h2 ----
    {
      const int hoff = isQ ? 64 : 0;
      float h2_0 = isQ ? sh[P_BQ1 + l32] : sh[P_BT1 + l32];
      float h2_1 = h2_0;
      #pragma unroll
      for (int q = 0; q < 16; q++) {
        const float4 w  = *(const float4*)&sh[P_W1 + q*256 + lane*4];
        const float4 a0 = *(const float4*)&act0[A_H1 + hoff + 4*q];
        const float4 a1 = *(const float4*)&act1[A_H1 + hoff + 4*q];
        h2_0 = fmaf(a0.x, w.x, h2_0); h2_1 = fmaf(a1.x, w.x, h2_1);
        h2_0 = fmaf(a0.y, w.y, h2_0); h2_1 = fmaf(a1.y, w.y, h2_1);
        h2_0 = fmaf(a0.z, w.z, h2_0); h2_1 = fmaf(a1.z, w.z, h2_1);
        h2_0 = fmaf(a0.w, w.w, h2_0); h2_1 = fmaf(a1.w, w.w, h2_1);
      }
      act0[A_H2 + lane] = fmaxf(h2_0, 0.f);
      act1[A_H2 + lane] = fmaxf(h2_1, 0.f);
    }

    // ---- mix + q0 ----
    float mix[2], q0v[2];
    {
      float mz0 = sh[P_MISC + 1], mz1 = mz0;
      float q00 = sh[P_BQ2 + c12], q01 = q00;
      #pragma unroll
      for (int q = 0; q < 8; q++) {
        const float4 wz  = *(const float4*)&sh[P_Z + 4*q];
        const float4 wq  = *(const float4*)&sh[P_Q2 + q*48 + c12*4];
        const float4 at0 = *(const float4*)&act0[A_H2 + 4*q];
        const float4 aq0 = *(const float4*)&act0[A_H2 + 32 + 4*q];
        const float4 at1 = *(const float4*)&act1[A_H2 + 4*q];
        const float4 aq1 = *(const float4*)&act1[A_H2 + 32 + 4*q];
        mz0 = fmaf(at0.x, wz.x, mz0); q00 = fmaf(aq0.x, wq.x, q00);
        mz0 = fmaf(at0.y, wz.y, mz0); q00 = fmaf(aq0.y, wq.y, q00);
        mz0 = fmaf(at0.z, wz.z, mz0); q00 = fmaf(aq0.z, wq.z, q00);
        mz0 = fmaf(at0.w, wz.w, mz0); q00 = fmaf(aq0.w, wq.w, q00);
        mz1 = fmaf(at1.x, wz.x, mz1); q01 = fmaf(aq1.x, wq.x, q01);
        mz1 = fmaf(at1.y, wz.y, mz1); q01 = fmaf(aq1.y, wq.y, q01);
        mz1 = fmaf(at1.z, wz.z, mz1); q01 = fmaf(aq1.z, wq.z, q01);
        mz1 = fmaf(at1.w, wz.w, mz1); q01 = fmaf(aq1.w, wq.w, q01);
      }
      mix[0] = 1.f / (1.f + expf(-mz0));
      mix[1] = 1.f / (1.f + expf(-mz1));
      q0v[0] = q00; q0v[1] = q01;
    }

    // ---- update + outputs + next {f,ax,ay} ----
    #pragma unroll
    for (int j = 0; j < 2; j++) {
      const int wid = nb + j;
      float* actj = j ? act1 : act0;
      const float newv = f_c[j] + mix[j]*udiff[j] + (1.f - mix[j])*urig[j] + q0v[j];
      if (lane < 12) {
        actj[A_NV + lane] = newv;
        if (use_stage) stg[(size_t)t*BN*12 + wid*12 + lane] = q0v[j];
        else           out[OQ0 + (wid*12 + lane)*TS + t] = q0v[j];
        out[OFD + (wid*TS + t)*12 + lane] = newv;
        fdst[wid*12 + lane] = newv;
        float mass = (newv == 0.f) ? 1.f : newv;
        float gpxn = ws[O_GPX + wid], gpyn = ws[O_GPY + wid];
        float axn = fminf(fmaxf(gpxn*mcv/mass, -2.f), 2.f);
        float ayn = fminf(fmaxf(gpyn*mcv/mass, -2.f), 2.f);
        a4dst[wid*12 + lane] = make_float4(newv, axn, ayn, 0.f);
      }
      if (lane == 0) out[OMIX + wid*TS + t] = mix[j];
    }

    // ---- dec ----
    {
      float d1_0 = ws[O_H1D + nb*32 + l32];
      float d1_1 = ws[O_H1D + (nb+1)*32 + l32];
      #pragma unroll
      for (int q = 0; q < 3; q++) {
        const float4 w  = *(const float4*)&sh[P_D0 + q*128 + l32*4];
        const float4 a0 = *(const float4*)&act0[A_NV + 4*q];
        const float4 a1 = *(const float4*)&act1[A_NV + 4*q];
        d1_0 = fmaf(a0.x, w.x, d1_0); d1_1 = fmaf(a1.x, w.x, d1_1);
        d1_0 = fmaf(a0.y, w.y, d1_0); d1_1 = fmaf(a1.y, w.y, d1_1);
        d1_0 = fmaf(a0.z, w.z, d1_0); d1_1 = fmaf(a1.z, w.z, d1_1);
        d1_0 = fmaf(a0.w, w.w, d1_0); d1_1 = fmaf(a1.w, w.w, d1_1);
      }
      if (lane < 32) {
        act0[A_D1 + lane] = fmaxf(d1_0, 0.f);
        act1[A_D1 + lane] = fmaxf(d1_1, 0.f);
      }
    }
    {
      float d2_0 = sh[P_BD1 + l32], d2_1 = d2_0;
      #pragma unroll
      for (int q = 0; q < 8; q++) {
        const float4 w  = *(const float4*)&sh[P_D1 + q*128 + l32*4];
        const float4 a0 = *(const float4*)&act0[A_D1 + 4*q];
        const float4 a1 = *(const float4*)&act1[A_D1 + 4*q];
        d2_0 = fmaf(a0.x, w.x, d2_0); d2_1 = fmaf(a1.x, w.x, d2_1);
        d2_0 = fmaf(a0.y, w.y, d2_0); d2_1 = fmaf(a1.y, w.y, d2_1);
        d2_0 = fmaf(a0.z, w.z, d2_0); d2_1 = fmaf(a1.z, w.z, d2_1);
        d2_0 = fmaf(a0.w, w.w, d2_0); d2_1 = fmaf(a1.w, w.w, d2_1);
      }
      if (lane < 32) {
        act0[A_D2 + lane] = fmaxf(d2_0, 0.f);
        act1[A_D2 + lane] = fmaxf(d2_1, 0.f);
      }
    }
    {
      float d3_0 = sh[P_BD2 + lane], d3_1 = d3_0;
      #pragma unroll
      for (int q = 0; q < 8; q++) {
        const float4 w  = *(const float4*)&sh[P_D2 + q*256 + lane*4];
        const float4 a0 = *(const float4*)&act0[A_D2 + 4*q];
        const float4 a1 = *(const float4*)&act1[A_D2 + 4*q];
        d3_0 = fmaf(a0.x, w.x, d3_0); d3_1 = fmaf(a1.x, w.x, d3_1);
        d3_0 = fmaf(a0.y, w.y, d3_0); d3_1 = fmaf(a1.y, w.y, d3_1);
        d3_0 = fmaf(a0.z, w.z, d3_0); d3_1 = fmaf(a1.z, w.z, d3_1);
        d3_0 = fmaf(a0.w, w.w, d3_0); d3_1 = fmaf(a1.w, w.w, d3_1);
      }
      const float wd3 = sh[P_D3 + lane];
      float u0 = fmaxf(d3_0, 0.f) * wd3;
      float u1 = fmaxf(d3_1, 0.f) * wd3;
      #pragma unroll
      for (int s2 = 32; s2 > 0; s2 >>= 1) {
        u0 += __shfl_xor(u0, s2);
        u1 += __shfl_xor(u1, s2);
      }
      if (lane == 0) {
        const float b3 = sh[P_MISC + 0];
        out[OUS + nb*TS + t]     = u0 + b3;
        out[OUS + (nb+1)*TS + t] = u1 + b3;
      }
    }
  }
}

// ---------------------------------------------------------------------------
// Final reorder: staged step-major q0 -> (B,N,12,1,T) layout.
// ---------------------------------------------------------------------------
__global__ void k_out(const float* __restrict__ stg, float* __restrict__ out) {
  const size_t NQ = (size_t)BN*12*TS;
  size_t i = (size_t)blockIdx.x * blockDim.x + threadIdx.x;
  if (i < NQ) {
    int e = (int)(i / TS), t = (int)(i % TS);
    out[OQ0 + i] = stg[(size_t)t*BN*12 + e];
  }
}

// ---------------------------------------------------------------------------
extern "C" void kernel_launch(void* const* d_in, const int* in_sizes, int n_in,
                              void* d_out, int out_size, void* d_ws, size_t ws_size,
                              hipStream_t stream) {
  const float* phi     = (const float*)d_in[0];
  const float* feat_dy = (const float*)d_in[1];
  const float* feat_st = (const float*)d_in[2];
  const float* Dv      = (const float*)d_in[3];
  const float* muv     = (const float*)d_in[4];
  const float* cv      = (const float*)d_in[5];
  const int*   adj4    = (const int*)d_in[6];
  const int*   adj25   = (const int*)d_in[7];
  const float* Wt0 = (const float*)d_in[8];
  const float* bt0 = (const float*)d_in[9];
  const float* Wt1 = (const float*)d_in[10];
  const float* bt1 = (const float*)d_in[11];
  const float* Wt2 = (const float*)d_in[12];
  const float* bt2 = (const float*)d_in[13];
  const float* Wq0 = (const float*)d_in[14];
  const float* bq0 = (const float*)d_in[15];
  const float* Wq1 = (const float*)d_in[16];
  const float* bq1 = (const float*)d_in[17];
  const float* Wq2 = (const float*)d_in[18];
  const float* bq2 = (const float*)d_in[19];
  const float* Wd0 = (const float*)d_in[20];
  const float* bd0 = (const float*)d_in[21];
  const float* Wd1 = (const float*)d_in[22];
  const float* bd1 = (const float*)d_in[23];
  const float* Wd2 = (const float*)d_in[24];
  const float* bd2 = (const float*)d_in[25];
  const float* Wd3 = (const float*)d_in[26];
  const float* bd3 = (const float*)d_in[27];

  float* ws  = (float*)d_ws;
  int*   wsi = (int*)(ws + O_FLTEND);
  float* out = (float*)d_out;
  const int use_stage = (ws_size >= WS_NEED) ? 1 : 0;
  float* stg = ws + O_STG;

  k_setup_small<<<1, 256, 0, stream>>>(Dv, muv, cv, ws);
  k_xpose<<<16, 256, 0, stream>>>(Wt0, Wq0, Wt1, Wq1, Wt2, Wq2, Wd0, Wd1, Wd2, Wd3,
                                  bt1, bq1, bt2, bq2, bd1, bd2, bd3, ws);
  k_setup_node<<<BN/4, 256, 0, stream>>>(phi, feat_dy, feat_st, adj4, adj25,
                                         Wt0, bt0, Wq0, bq0, Wd0, bd0, ws, wsi);
  k_build_rev<<<(BN*25 + 255)/256, 256, 0, stream>>>(adj25, wsi);

  float* fa = ws + O_FEATA; float* fb = ws + O_FEATB;
  float4* pa = (float4*)(ws + O_AXY4A);
  float4* pb = (float4*)(ws + O_AXY4B);
  for (int t = 0; t < TS; t++) {
    k_step<<<BN/32, 512, 0, stream>>>(ws, wsi, wsi + BN, t, fa, pa, fb, pb,
                                      adj4, adj25, stg, use_stage, out);
    float* tf = fa; fa = fb; fb = tf;
    float4* tp = pa; pa = pb; pb = tp;
  }
  if (use_stage) {
    const size_t tot = (size_t)BN*12*TS;
    k_out<<<(unsigned)((tot + 255)/256), 256, 0, stream>>>(stg, out);
  }
}